// Round 2
// baseline (859.334 us; speedup 1.0000x reference)
//
#include <hip/hip_runtime.h>
#include <hip/hip_bf16.h>

typedef unsigned short ushort_t;
typedef short bf16x8 __attribute__((ext_vector_type(8)));
typedef ushort_t u16x8 __attribute__((ext_vector_type(8)));
typedef float f32x4 __attribute__((ext_vector_type(4)));

#define DEV static __device__ __forceinline__
#define SCOPE_AGENT __HIP_MEMORY_SCOPE_AGENT

DEV float bf2f(ushort_t u) { unsigned v = ((unsigned)u) << 16; float f; __builtin_memcpy(&f, &v, 4); return f; }
DEV short f2bf(float x) { __hip_bfloat16 h = __float2bfloat16(x); short s; __builtin_memcpy(&s, &h, 2); return s; }
DEV float sigm(float x) { return 1.0f / (1.0f + __expf(-x)); }
DEV unsigned pk2(float a, float b) {
    return ((unsigned)(ushort_t)f2bf(a)) | (((unsigned)(ushort_t)f2bf(b)) << 16);
}
DEV float upk(unsigned u, int hi) { return bf2f((ushort_t)(hi ? (u >> 16) : (u & 0xffffu))); }

// agent-scope coherent helpers (correct across XCD L2s, no fence reliance)
DEV float aload(const float* p) { return __hip_atomic_load((float*)p, __ATOMIC_RELAXED, SCOPE_AGENT); }
DEV void astore(float* p, float v) { __hip_atomic_store(p, v, __ATOMIC_RELAXED, SCOPE_AGENT); }
DEV void afadd(float* p, float v) { __hip_atomic_fetch_add(p, v, __ATOMIC_RELAXED, SCOPE_AGENT); }

DEV bf16x8 cvt8(float4 a0, float4 a1) {
    bf16x8 t;
    t[0] = f2bf(a0.x); t[1] = f2bf(a0.y); t[2] = f2bf(a0.z); t[3] = f2bf(a0.w);
    t[4] = f2bf(a1.x); t[5] = f2bf(a1.y); t[6] = f2bf(a1.z); t[7] = f2bf(a1.w);
    return t;
}
DEV bf16x8 ld8f(const float* __restrict__ p) {
    return cvt8(*reinterpret_cast<const float4*>(p), *reinterpret_cast<const float4*>(p + 4));
}
DEV bf16x8 ld8fs(const float* __restrict__ p, float s) {
    float4 a0 = *reinterpret_cast<const float4*>(p);
    float4 a1 = *reinterpret_cast<const float4*>(p + 4);
    a0.x *= s; a0.y *= s; a0.z *= s; a0.w *= s;
    a1.x *= s; a1.y *= s; a1.z *= s; a1.w *= s;
    return cvt8(a0, a1);
}

// grid barrier: 16 stripes of 34 blocks -> master. ord is the 1-based barrier ordinal.
DEV void gbar(int* bar, int ord) {
    __syncthreads();
    if (threadIdx.x == 0) {
        int s = blockIdx.x & 15;
        int v = __hip_atomic_fetch_add(&bar[s], 1, __ATOMIC_ACQ_REL, SCOPE_AGENT);
        if (v == ord * 34 - 1)
            __hip_atomic_fetch_add(&bar[16], 1, __ATOMIC_ACQ_REL, SCOPE_AGENT);
        while (__hip_atomic_load(&bar[16], __ATOMIC_ACQUIRE, SCOPE_AGENT) < ord * 16)
            __builtin_amdgcn_s_sleep(8);
    }
    __syncthreads();
}

// ---------------- K0: fp32 -> bf16 for hidden, W1, Wv; also re-arm barrier counters
__global__ void k_cvt(const float* __restrict__ h, const float* __restrict__ W1,
                      const float* __restrict__ Wv, ushort_t* __restrict__ Hb,
                      ushort_t* __restrict__ Wcat, int* __restrict__ bar) {
    if (blockIdx.x == 0 && threadIdx.x < 32) bar[threadIdx.x] = 0;
    long i = (long)blockIdx.x * 256 + threadIdx.x;
    const float* src;
    ushort_t* dst;
    if (i < 1048576) { src = h + i * 8; dst = Hb + i * 8; }
    else if (i < 1056768) { long j = i - 1048576; src = W1 + j * 8; dst = Wcat + j * 8; }
    else { long j = i - 1056768; src = Wv + j * 8; dst = Wcat + 65536 + j * 8; }
    const float4* p = reinterpret_cast<const float4*>(src);
    *reinterpret_cast<bf16x8*>(dst) = cvt8(p[0], p[1]);
}

// ---------------- K1: Ff[8192][64] = Hb@W1^T (fp32), VbT[64][8192] = (Hb@Wv^T)^T bf16
__global__ __launch_bounds__(256) void k_fv(const ushort_t* __restrict__ Hb,
        const ushort_t* __restrict__ Wcat,
        float* __restrict__ Ff, ushort_t* __restrict__ VbT) {
    int m0 = blockIdx.x * 16;
    int wave = threadIdx.x >> 6, lane = threadIdx.x & 63;
    int l16 = lane & 15, quad = lane >> 4;
    int cb = (wave & 1) * 32;
    int brow_off = (wave < 2) ? 0 : 64;   // rows 0-63 = W1, 64-127 = Wv
    f32x4 acc[2] = {};
    const ushort_t* arow = Hb + (long)(m0 + l16) * 1024;
    const ushort_t* brow0 = Wcat + (long)(brow_off + cb + l16) * 1024;
    const ushort_t* brow1 = Wcat + (long)(brow_off + cb + 16 + l16) * 1024;
    for (int kc = 0; kc < 1024; kc += 128) {
        bf16x8 a4[4], b04[4], b14[4];
#pragma unroll
        for (int u = 0; u < 4; u++) {
            int ko = kc + u * 32 + quad * 8;
            a4[u] = *reinterpret_cast<const bf16x8*>(arow + ko);
            b04[u] = *reinterpret_cast<const bf16x8*>(brow0 + ko);
            b14[u] = *reinterpret_cast<const bf16x8*>(brow1 + ko);
        }
#pragma unroll
        for (int u = 0; u < 4; u++) {
            acc[0] = __builtin_amdgcn_mfma_f32_16x16x32_bf16(a4[u], b04[u], acc[0], 0, 0, 0);
            acc[1] = __builtin_amdgcn_mfma_f32_16x16x32_bf16(a4[u], b14[u], acc[1], 0, 0, 0);
        }
    }
    bool isV = (wave >= 2);
#pragma unroll
    for (int c = 0; c < 2; c++)
#pragma unroll
        for (int rr = 0; rr < 4; rr++) {
            int row = m0 + quad * 4 + rr;
            int col = cb + c * 16 + l16;
            float v = acc[c][rr];
            if (!isV) Ff[row * 64 + col] = v;
            else VbT[(long)col * 8192 + row] = (ushort_t)f2bf(v);
        }
}

// ---------------- K2: gelu -> features -> Q,K,charge0. 256 blocks x 32 rows.
__global__ __launch_bounds__(256) void k_feat(const float* __restrict__ Ff,
        const float* __restrict__ b1, const float* __restrict__ W2, const float* __restrict__ b2,
        const float* __restrict__ Wq, const float* __restrict__ Wk,
        const float* __restrict__ Wc, const float* __restrict__ bc,
        ushort_t* __restrict__ Qb, ushort_t* __restrict__ Kb,
        float* __restrict__ charge0) {
    __shared__ float w2L[28 * 65], wqL[64 * 29], wkL[64 * 29], wcL[28], b2L[28];
    __shared__ float fL[4][64], featL[4][28];
    int tid = threadIdx.x;
    for (int i = tid; i < 28 * 64; i += 256) w2L[(i >> 6) * 65 + (i & 63)] = W2[i];
    for (int i = tid; i < 64 * 28; i += 256) {
        int r = i / 28, c = i - r * 28;
        wqL[r * 29 + c] = Wq[i];
        wkL[r * 29 + c] = Wk[i];
    }
    if (tid < 28) { wcL[tid] = Wc[tid]; b2L[tid] = b2[tid]; }
    __syncthreads();
    int w = tid >> 6, lane = tid & 63;
    float b1v = b1[lane];
    float bcv = bc[0];
    for (int it = 0; it < 8; it++) {
        int row = blockIdx.x * 32 + it * 4 + w;
        float x = Ff[row * 64 + lane] + b1v;
        fL[w][lane] = 0.5f * x * (1.0f + erff(x * 0.70710678118654752f));
        __syncthreads();
        if (lane < 28) {
            float s = b2L[lane];
#pragma unroll
            for (int j = 0; j < 64; j++) s += fL[w][j] * w2L[lane * 65 + j];
            featL[w][lane] = sigm(s);
        }
        __syncthreads();
        float q = 0.f, k = 0.f;
#pragma unroll
        for (int i = 0; i < 28; i++) {
            float fv = featL[w][i];
            q += fv * wqL[lane * 29 + i];
            k += fv * wkL[lane * 29 + i];
        }
        Qb[row * 64 + lane] = (ushort_t)f2bf(q * 0.125f);  // fold 1/sqrt(64)
        Kb[row * 64 + lane] = (ushort_t)f2bf(k);
        if (lane == 0) {
            float c = bcv;
#pragma unroll
            for (int i = 0; i < 28; i++) c += featL[w][i] * wcL[i];
            charge0[row] = sigm(c);
        }
        __syncthreads();
    }
}

DEV void tri_decode(int r, int& ti, int& tj) {
    int t = (int)((sqrtf(8.f * (float)r + 1.f) - 1.f) * 0.5f);
    while ((t + 1) * (t + 2) / 2 <= r) t++;
    while (t * (t + 1) / 2 > r) t--;
    ti = t;
    tj = r - t * (t + 1) / 2;
}

// ---------------- FUSED persistent kernel: compat MFMA (regs) + 4x(rowsum, colsum,
// local charge update) + final PV, with 9 hand-rolled grid barriers.
// Grid MUST be 544 = 4 batches x 136 causal 128x128 tiles; 3 blocks/CU co-resident
// (LDS 36.9 KB/block, launch_bounds forces VGPR fit).
__global__ __launch_bounds__(256, 3) void k_fused(
        const ushort_t* __restrict__ Qb, const ushort_t* __restrict__ Kb,
        const ushort_t* __restrict__ VbT, const float* __restrict__ charge0,
        const float* __restrict__ stepp, const float* __restrict__ decayp,
        float* __restrict__ Lbuf,    // [5][8192] row softmax denominators per stage
        float* __restrict__ Rbuf,    // [4][8192] received per iteration
        float* __restrict__ Oacc,    // [8192][64] unnormalized PV accumulator
        int* bar) {
    __shared__ float chRn[128], chCn[128];   // current charge, tile rows / cols
    __shared__ float LiL[128], colacc[128];
    __shared__ __align__(16) ushort_t pstage[4][32][136];  // final-phase p (per wave), padded

    int bid = blockIdx.x, tid = threadIdx.x;
    int b = bid & 3, r = bid >> 2, ti, tj;
    tri_decode(r, ti, tj);
    int wave = tid >> 6, lane = tid & 63, l16 = lane & 15, quad = lane >> 4;
    bool diag = (ti == tj);
    float step = stepp[0], decay = decayp[0];

    // zero Oacc+Lbuf+Rbuf (contiguous: 524288+40960+32768 = 598016 floats) with
    // agent-scope stores so no XCD-local dirty lines can later clobber atomics.
    for (int i = bid * 256 + tid; i < 598016; i += 544 * 256) astore(&Oacc[i], 0.f);
    if (tid < 128) chRn[tid] = charge0[b * 2048 + ti * 128 + tid];
    else chCn[tid - 128] = charge0[b * 2048 + tj * 128 + (tid - 128)];

    // ---- compat tile via MFMA, kept in registers (packed bf16)
    int rbase = b * 2048 + ti * 128 + wave * 32;
    int cbase = b * 2048 + tj * 128;
    unsigned cpk[2][8][2];
    {
        f32x4 acc[2][8] = {};
#pragma unroll
        for (int kc = 0; kc < 64; kc += 32) {
            int ko = kc + quad * 8;
            bf16x8 af[2], bfm[8];
#pragma unroll
            for (int f = 0; f < 2; f++)
                af[f] = *reinterpret_cast<const bf16x8*>(Qb + (long)(rbase + f * 16 + l16) * 64 + ko);
#pragma unroll
            for (int f = 0; f < 8; f++)
                bfm[f] = *reinterpret_cast<const bf16x8*>(Kb + (long)(cbase + f * 16 + l16) * 64 + ko);
#pragma unroll
            for (int i = 0; i < 2; i++)
#pragma unroll
                for (int j = 0; j < 8; j++)
                    acc[i][j] = __builtin_amdgcn_mfma_f32_16x16x32_bf16(af[i], bfm[j], acc[i][j], 0, 0, 0);
        }
#pragma unroll
        for (int i = 0; i < 2; i++)
#pragma unroll
            for (int j = 0; j < 8; j++) {
                cpk[i][j][0] = pk2(acc[i][j][0], acc[i][j][1]);
                cpk[i][j][1] = pk2(acc[i][j][2], acc[i][j][3]);
            }
    }
    float dot[2][8][4] = {};  // running sum_s c_s[n]*c_s[m] per owned (row,col) pair

    // local charge update from completed Rbuf[t-1], then fold into running dot
    auto upd = [&](int t) {
        const float* Rp = Rbuf + (long)(t - 1) * 8192 + b * 2048;
        if (tid < 128) chRn[tid] *= (1.f - decay * sigm(aload(&Rp[ti * 128 + tid]) - 1.f));
        else { int m = tid - 128; chCn[m] *= (1.f - decay * sigm(aload(&Rp[tj * 128 + m]) - 1.f)); }
        __syncthreads();
        float rv[2][4], cv[8];
#pragma unroll
        for (int i = 0; i < 2; i++)
#pragma unroll
            for (int rr = 0; rr < 4; rr++) rv[i][rr] = chRn[wave * 32 + i * 16 + quad * 4 + rr];
#pragma unroll
        for (int j = 0; j < 8; j++) cv[j] = chCn[j * 16 + l16];
#pragma unroll
        for (int i = 0; i < 2; i++)
#pragma unroll
            for (int j = 0; j < 8; j++)
#pragma unroll
                for (int rr = 0; rr < 4; rr++) dot[i][j][rr] += rv[i][rr] * cv[j];
    };

    // reduce row-sums across the 16-lane group and push coherent atomics
    auto rowred = [&](float (&S)[2][4], float* Lt) {
#pragma unroll
        for (int i = 0; i < 2; i++)
#pragma unroll
            for (int rr = 0; rr < 4; rr++) {
                float s = S[i][rr];
                s += __shfl_xor(s, 1); s += __shfl_xor(s, 2);
                s += __shfl_xor(s, 4); s += __shfl_xor(s, 8);
                S[i][rr] = s;
            }
#pragma unroll
        for (int e = 0; e < 8; e++) {
            int i = e >> 2, rr = e & 3;
            if (l16 == e) afadd(&Lt[i * 16 + quad * 4 + rr], S[i][rr]);
        }
    };

    int ord = 0;
    gbar(bar, ++ord);  // (1) zero visible everywhere

    for (int t = 0; t < 4; ++t) {
        if (t > 0) upd(t);
        // ---- row pass: partial L[n]
        float S[2][4] = {};
#pragma unroll
        for (int i = 0; i < 2; i++)
#pragma unroll
            for (int rr = 0; rr < 4; rr++) {
                int rl = wave * 32 + i * 16 + quad * 4 + rr;
                float s = 0.f;
#pragma unroll
                for (int j = 0; j < 8; j++) {
                    float c = upk(cpk[i][j][rr >> 1], rr & 1);
                    float sg = fmaf(step, dot[i][j][rr], 1.f);
                    float p = __expf(c * sg);
                    if (diag && (j * 16 + l16) > rl) p = 0.f;
                    s += p;
                }
                S[i][rr] = s;
            }
        rowred(S, Lbuf + (long)t * 8192 + b * 2048 + ti * 128 + wave * 32);
        gbar(bar, ++ord);

        // ---- col pass: received[m] += sum_n p/L[n]
        if (tid < 128) {
            LiL[tid] = 1.f / fmaxf(aload(&Lbuf[(long)t * 8192 + b * 2048 + ti * 128 + tid]), 1e-30f);
            colacc[tid] = 0.f;
        }
        __syncthreads();
        float colS[8] = {};
#pragma unroll
        for (int i = 0; i < 2; i++)
#pragma unroll
            for (int rr = 0; rr < 4; rr++) {
                int rl = wave * 32 + i * 16 + quad * 4 + rr;
                float li = LiL[rl];
#pragma unroll
                for (int j = 0; j < 8; j++) {
                    float c = upk(cpk[i][j][rr >> 1], rr & 1);
                    float sg = fmaf(step, dot[i][j][rr], 1.f);
                    float p = __expf(c * sg) * li;
                    if (diag && (j * 16 + l16) > rl) p = 0.f;
                    colS[j] += p;
                }
            }
#pragma unroll
        for (int j = 0; j < 8; j++) {
            float s = colS[j];
            s += __shfl_xor(s, 16); s += __shfl_xor(s, 32);
            if (quad == 0) atomicAdd(&colacc[j * 16 + l16], s);
        }
        __syncthreads();
        if (tid < 128) afadd(&Rbuf[(long)t * 8192 + b * 2048 + tj * 128 + tid], colacc[tid]);
        gbar(bar, ++ord);
    }

    // ---- final: charge_4, p with sg_4, L4 row sums, PV MFMA, unnormalized Oacc
    upd(4);
    {
        float S[2][4] = {};
#pragma unroll
        for (int i = 0; i < 2; i++)
#pragma unroll
            for (int rr = 0; rr < 4; rr++) {
                int rl = wave * 32 + i * 16 + quad * 4 + rr;
                float s = 0.f;
#pragma unroll
                for (int j = 0; j < 8; j++) {
                    float c = upk(cpk[i][j][rr >> 1], rr & 1);
                    float sg = fmaf(step, dot[i][j][rr], 1.f);
                    float p = __expf(c * sg);
                    if (diag && (j * 16 + l16) > rl) p = 0.f;
                    s += p;
                    pstage[wave][i * 16 + quad * 4 + rr][j * 16 + l16] = (ushort_t)f2bf(p);
                }
                S[i][rr] = s;
            }
        rowred(S, Lbuf + 4L * 8192 + b * 2048 + ti * 128 + wave * 32);
    }
    __syncthreads();
    {
        f32x4 po[2][4] = {};
#pragma unroll
        for (int kc4 = 0; kc4 < 4; kc4++) {
            int mk = kc4 * 32 + quad * 8;
            bf16x8 pa[2], vf[4];
#pragma unroll
            for (int i = 0; i < 2; i++)
                pa[i] = *reinterpret_cast<const bf16x8*>(&pstage[wave][i * 16 + l16][mk]);
#pragma unroll
            for (int f = 0; f < 4; f++)
                vf[f] = *reinterpret_cast<const bf16x8*>(VbT + (long)(f * 16 + l16) * 8192 + cbase + mk);
#pragma unroll
            for (int i = 0; i < 2; i++)
#pragma unroll
                for (int f = 0; f < 4; f++)
                    po[i][f] = __builtin_amdgcn_mfma_f32_16x16x32_bf16(pa[i], vf[f], po[i][f], 0, 0, 0);
        }
#pragma unroll
        for (int i = 0; i < 2; i++)
#pragma unroll
            for (int f = 0; f < 4; f++)
#pragma unroll
                for (int rr = 0; rr < 4; rr++)
                    afadd(&Oacc[(long)(rbase + i * 16 + quad * 4 + rr) * 64 + f * 16 + l16],
                          po[i][f][rr]);
    }
}

// ---------------- out = ((Oacc/L4) @ Wo^T) * 0.1, fp32 store
__global__ __launch_bounds__(256) void k_oproj(const float* __restrict__ Oacc,
                                               const float* __restrict__ Lrow4,
                                               const float* __restrict__ Wo,
                                               float* __restrict__ out) {
    int mt = blockIdx.x & 63, nt = blockIdx.x >> 6;
    int wave = threadIdx.x >> 6, lane = threadIdx.x & 63;
    int wm = wave >> 1, wn = wave & 1;
    int l16 = lane & 15, quad = lane >> 4;
    int row0 = mt * 128 + wm * 64;
    int col0 = nt * 128 + wn * 64;
    float sA[4];
#pragma unroll
    for (int f = 0; f < 4; f++)
        sA[f] = 1.f / fmaxf(Lrow4[row0 + f * 16 + l16], 1e-30f);
    f32x4 acc[4][4] = {};
#pragma unroll
    for (int kc = 0; kc < 64; kc += 32) {
        int ko = kc + quad * 8;
        bf16x8 af[4], bfm[4];
#pragma unroll
        for (int f = 0; f < 4; f++) af[f] = ld8fs(Oacc + (long)(row0 + f * 16 + l16) * 64 + ko, sA[f]);
#pragma unroll
        for (int f = 0; f < 4; f++) bfm[f] = ld8f(Wo + (long)(col0 + f * 16 + l16) * 64 + ko);
#pragma unroll
        for (int i = 0; i < 4; i++)
#pragma unroll
            for (int j = 0; j < 4; j++)
                acc[i][j] = __builtin_amdgcn_mfma_f32_16x16x32_bf16(af[i], bfm[j], acc[i][j], 0, 0, 0);
    }
#pragma unroll
    for (int i = 0; i < 4; i++)
#pragma unroll
        for (int j = 0; j < 4; j++)
#pragma unroll
            for (int rr = 0; rr < 4; rr++) {
                long rowg = row0 + i * 16 + quad * 4 + rr;
                int colg = col0 + j * 16 + l16;
                out[rowg * 1024 + colg] = acc[i][j][rr] * 0.1f;
            }
}

extern "C" void kernel_launch(void* const* d_in, const int* in_sizes, int n_in,
                              void* d_out, int out_size, void* d_ws, size_t ws_size,
                              hipStream_t stream) {
    const float* hidden = (const float*)d_in[0];
    const float* W1 = (const float*)d_in[1];
    const float* b1 = (const float*)d_in[2];
    const float* W2 = (const float*)d_in[3];
    const float* b2 = (const float*)d_in[4];
    const float* Wq = (const float*)d_in[5];
    const float* Wk = (const float*)d_in[6];
    const float* Wc = (const float*)d_in[7];
    const float* bc = (const float*)d_in[8];
    const float* Wv = (const float*)d_in[9];
    const float* Wo = (const float*)d_in[10];
    const float* stepp = (const float*)d_in[11];
    const float* decayp = (const float*)d_in[12];

    char* ws = (char*)d_ws;
    size_t off = 0;
    auto alloc = [&](size_t bytes) {
        void* p = ws + off;
        off += (bytes + 255) & ~(size_t)255;
        return p;
    };
    ushort_t* Hb = (ushort_t*)alloc(8192UL * 1024 * 2);   // 16 MiB bf16 hidden
    ushort_t* Wcat = (ushort_t*)alloc(128UL * 1024 * 2);  // W1;Wv bf16
    float* Ff = (float*)alloc(8192UL * 64 * 4);           // 2 MiB
    ushort_t* Qb = (ushort_t*)alloc(8192UL * 64 * 2);
    ushort_t* Kb = (ushort_t*)alloc(8192UL * 64 * 2);
    ushort_t* VbT = (ushort_t*)alloc(64UL * 8192 * 2);
    float* charge0 = (float*)alloc(8192UL * 4);
    // The next three MUST stay contiguous (k_fused zeroes them as one range):
    float* Oacc = (float*)alloc(8192UL * 64 * 4);  // 2 MiB   (524288 floats)
    float* Lbuf = (float*)alloc(5UL * 8192 * 4);   // 160 KiB (40960 floats)
    float* Rbuf = (float*)alloc(4UL * 8192 * 4);   // 128 KiB (32768 floats)
    int* bar = (int*)alloc(256);                   // 16 stripes + master
    (void)ws_size; (void)in_sizes; (void)n_in; (void)out_size;

    k_cvt<<<4160, 256, 0, stream>>>(hidden, W1, Wv, Hb, Wcat, bar);
    k_fv<<<512, 256, 0, stream>>>(Hb, Wcat, Ff, VbT);
    k_feat<<<256, 256, 0, stream>>>(Ff, b1, W2, b2, Wq, Wk, Wc, bc, Qb, Kb, charge0);
    k_fused<<<544, 256, 0, stream>>>(Qb, Kb, VbT, charge0, stepp, decayp,
                                     Lbuf, Rbuf, Oacc, bar);
    k_oproj<<<512, 256, 0, stream>>>(Oacc, Lbuf + 4L * 8192, Wo, (float*)d_out);
}

// Round 3
// 768.925 us; speedup vs baseline: 1.1176x; 1.1176x over previous
//
#include <hip/hip_runtime.h>
#include <hip/hip_bf16.h>

typedef unsigned short ushort_t;
typedef short bf16x8 __attribute__((ext_vector_type(8)));
typedef ushort_t u16x8 __attribute__((ext_vector_type(8)));
typedef ushort_t u16x4 __attribute__((ext_vector_type(4)));
typedef float f32x4 __attribute__((ext_vector_type(4)));

#define DEV static __device__ __forceinline__
#define SCOPE_AGENT __HIP_MEMORY_SCOPE_AGENT
#define NBLK 544

DEV float bf2f(ushort_t u) { unsigned v = ((unsigned)u) << 16; float f; __builtin_memcpy(&f, &v, 4); return f; }
DEV short f2bf(float x) { __hip_bfloat16 h = __float2bfloat16(x); short s; __builtin_memcpy(&s, &h, 2); return s; }
DEV float sigm(float x) { return 1.0f / (1.0f + __expf(-x)); }
DEV unsigned pk2(float a, float b) {
    return ((unsigned)(ushort_t)f2bf(a)) | (((unsigned)(ushort_t)f2bf(b)) << 16);
}
DEV float upk(unsigned u, int hi) { return bf2f((ushort_t)(hi ? (u >> 16) : (u & 0xffffu))); }

// agent-scope coherent helpers (correct across XCD L2s)
DEV float aload(const float* p) { return __hip_atomic_load((float*)p, __ATOMIC_RELAXED, SCOPE_AGENT); }
DEV void astore(float* p, float v) { __hip_atomic_store(p, v, __ATOMIC_RELAXED, SCOPE_AGENT); }
DEV void afadd(float* p, float v) { __hip_atomic_fetch_add(p, v, __ATOMIC_RELAXED, SCOPE_AGENT); }

DEV bf16x8 cvt8(float4 a0, float4 a1) {
    bf16x8 t;
    t[0] = f2bf(a0.x); t[1] = f2bf(a0.y); t[2] = f2bf(a0.z); t[3] = f2bf(a0.w);
    t[4] = f2bf(a1.x); t[5] = f2bf(a1.y); t[6] = f2bf(a1.z); t[7] = f2bf(a1.w);
    return t;
}
DEV bf16x8 ld8f(const float* __restrict__ p) {
    return cvt8(*reinterpret_cast<const float4*>(p), *reinterpret_cast<const float4*>(p + 4));
}

// grid barrier, contention-free:
//  - 32 arrival counters, each on its own 128B line (17 blocks/counter)
//  - block 0 polls the 32 counters (1 thread each), then releases via per-block
//    flags each on a private 64B line; every block spins on its OWN flag only.
// bar layout (ints): arrive[s] at bar[s*32] (s<32); relflag[b] at bar[1024+b*16].
// Total 9728 ints, re-zeroed by k_cvt each launch (graph replay safe).
DEV void gbar(int* bar, int ord) {
    __syncthreads();
    if (threadIdx.x == 0)
        __hip_atomic_fetch_add(&bar[(blockIdx.x & 31) * 32], 1, __ATOMIC_ACQ_REL, SCOPE_AGENT);
    if (blockIdx.x == 0) {
        if (threadIdx.x < 32)
            while (__hip_atomic_load(&bar[threadIdx.x * 32], __ATOMIC_ACQUIRE, SCOPE_AGENT) < ord * (NBLK / 32))
                __builtin_amdgcn_s_sleep(2);
        __syncthreads();
        for (int i = threadIdx.x; i < NBLK; i += 256)
            __hip_atomic_store(&bar[1024 + i * 16], ord, __ATOMIC_RELEASE, SCOPE_AGENT);
    }
    if (threadIdx.x == 0)
        while (__hip_atomic_load(&bar[1024 + blockIdx.x * 16], __ATOMIC_ACQUIRE, SCOPE_AGENT) < ord)
            __builtin_amdgcn_s_sleep(2);
    __syncthreads();
}

// ---------------- K0: fp32 -> bf16 for hidden, W1, Wv; also re-arm barrier region
__global__ void k_cvt(const float* __restrict__ h, const float* __restrict__ W1,
                      const float* __restrict__ Wv, ushort_t* __restrict__ Hb,
                      ushort_t* __restrict__ Wcat, int* __restrict__ bar) {
    long i = (long)blockIdx.x * 256 + threadIdx.x;
    if (i < 9728) bar[i] = 0;
    const float* src;
    ushort_t* dst;
    if (i < 1048576) { src = h + i * 8; dst = Hb + i * 8; }
    else if (i < 1056768) { long j = i - 1048576; src = W1 + j * 8; dst = Wcat + j * 8; }
    else { long j = i - 1056768; src = Wv + j * 8; dst = Wcat + 65536 + j * 8; }
    const float4* p = reinterpret_cast<const float4*>(src);
    *reinterpret_cast<bf16x8*>(dst) = cvt8(p[0], p[1]);
}

// ---------------- K1: Ff[8192][64] = Hb@W1^T (fp32), VbT[64][8192] = (Hb@Wv^T)^T bf16
__global__ __launch_bounds__(256) void k_fv(const ushort_t* __restrict__ Hb,
        const ushort_t* __restrict__ Wcat,
        float* __restrict__ Ff, ushort_t* __restrict__ VbT) {
    int m0 = blockIdx.x * 16;
    int wave = threadIdx.x >> 6, lane = threadIdx.x & 63;
    int l16 = lane & 15, quad = lane >> 4;
    int cb = (wave & 1) * 32;
    int brow_off = (wave < 2) ? 0 : 64;   // rows 0-63 = W1, 64-127 = Wv
    f32x4 acc[2] = {};
    const ushort_t* arow = Hb + (long)(m0 + l16) * 1024;
    const ushort_t* brow0 = Wcat + (long)(brow_off + cb + l16) * 1024;
    const ushort_t* brow1 = Wcat + (long)(brow_off + cb + 16 + l16) * 1024;
    for (int kc = 0; kc < 1024; kc += 128) {
        bf16x8 a4[4], b04[4], b14[4];
#pragma unroll
        for (int u = 0; u < 4; u++) {
            int ko = kc + u * 32 + quad * 8;
            a4[u] = *reinterpret_cast<const bf16x8*>(arow + ko);
            b04[u] = *reinterpret_cast<const bf16x8*>(brow0 + ko);
            b14[u] = *reinterpret_cast<const bf16x8*>(brow1 + ko);
        }
#pragma unroll
        for (int u = 0; u < 4; u++) {
            acc[0] = __builtin_amdgcn_mfma_f32_16x16x32_bf16(a4[u], b04[u], acc[0], 0, 0, 0);
            acc[1] = __builtin_amdgcn_mfma_f32_16x16x32_bf16(a4[u], b14[u], acc[1], 0, 0, 0);
        }
    }
    bool isV = (wave >= 2);
#pragma unroll
    for (int c = 0; c < 2; c++)
#pragma unroll
        for (int rr = 0; rr < 4; rr++) {
            int row = m0 + quad * 4 + rr;
            int col = cb + c * 16 + l16;
            float v = acc[c][rr];
            if (!isV) Ff[row * 64 + col] = v;
            else VbT[(long)col * 8192 + row] = (ushort_t)f2bf(v);
        }
}

// ---------------- K2: gelu -> features -> Q,K,charge0. 256 blocks x 32 rows.
__global__ __launch_bounds__(256) void k_feat(const float* __restrict__ Ff,
        const float* __restrict__ b1, const float* __restrict__ W2, const float* __restrict__ b2,
        const float* __restrict__ Wq, const float* __restrict__ Wk,
        const float* __restrict__ Wc, const float* __restrict__ bc,
        ushort_t* __restrict__ Qb, ushort_t* __restrict__ Kb,
        float* __restrict__ charge0) {
    __shared__ float w2L[28 * 65], wqL[64 * 29], wkL[64 * 29], wcL[28], b2L[28];
    __shared__ float fL[4][64], featL[4][28];
    int tid = threadIdx.x;
    for (int i = tid; i < 28 * 64; i += 256) w2L[(i >> 6) * 65 + (i & 63)] = W2[i];
    for (int i = tid; i < 64 * 28; i += 256) {
        int r = i / 28, c = i - r * 28;
        wqL[r * 29 + c] = Wq[i];
        wkL[r * 29 + c] = Wk[i];
    }
    if (tid < 28) { wcL[tid] = Wc[tid]; b2L[tid] = b2[tid]; }
    __syncthreads();
    int w = tid >> 6, lane = tid & 63;
    float b1v = b1[lane];
    float bcv = bc[0];
    for (int it = 0; it < 8; it++) {
        int row = blockIdx.x * 32 + it * 4 + w;
        float x = Ff[row * 64 + lane] + b1v;
        fL[w][lane] = 0.5f * x * (1.0f + erff(x * 0.70710678118654752f));
        __syncthreads();
        if (lane < 28) {
            float s = b2L[lane];
#pragma unroll
            for (int j = 0; j < 64; j++) s += fL[w][j] * w2L[lane * 65 + j];
            featL[w][lane] = sigm(s);
        }
        __syncthreads();
        float q = 0.f, k = 0.f;
#pragma unroll
        for (int i = 0; i < 28; i++) {
            float fv = featL[w][i];
            q += fv * wqL[lane * 29 + i];
            k += fv * wkL[lane * 29 + i];
        }
        Qb[row * 64 + lane] = (ushort_t)f2bf(q * 0.125f);  // fold 1/sqrt(64)
        Kb[row * 64 + lane] = (ushort_t)f2bf(k);
        if (lane == 0) {
            float c = bcv;
#pragma unroll
            for (int i = 0; i < 28; i++) c += featL[w][i] * wcL[i];
            charge0[row] = sigm(c);
        }
        __syncthreads();
    }
}

DEV void tri_decode(int r, int& ti, int& tj) {
    int t = (int)((sqrtf(8.f * (float)r + 1.f) - 1.f) * 0.5f);
    while ((t + 1) * (t + 2) / 2 <= r) t++;
    while (t * (t + 1) / 2 > r) t--;
    ti = t;
    tj = r - t * (t + 1) / 2;
}

// ---------------- FUSED persistent kernel: compat MFMA (regs) + 4x(rowsum, colsum,
// local charge update) + final PV, with 9 contention-free grid barriers.
// Grid MUST be 544 = 4 batches x 136 causal 128x128 tiles; 3 blocks/CU resident.
// PV partials go to per-tile slabs (plain stores) - reduced later by k_reduce.
__global__ __launch_bounds__(256, 3) void k_fused(
        const ushort_t* __restrict__ Qb, const ushort_t* __restrict__ Kb,
        const ushort_t* __restrict__ VbT, const float* __restrict__ charge0,
        const float* __restrict__ stepp, const float* __restrict__ decayp,
        float* __restrict__ Lbuf,    // [5][8192] row softmax denominators per stage
        float* __restrict__ Rbuf,    // [4][8192] received per iteration (contiguous after Lbuf)
        float* __restrict__ Opart,   // [544][128][64] per-tile PV partials
        int* bar) {
    __shared__ float chRn[128], chCn[128];   // current charge, tile rows / cols
    __shared__ float LiL[128], colacc[128];
    __shared__ __align__(16) ushort_t pstage[4][32][136];  // final-phase p (per wave), padded

    int bid = blockIdx.x, tid = threadIdx.x;
    int b = bid & 3, r = bid >> 2, ti, tj;
    tri_decode(r, ti, tj);
    int wave = tid >> 6, lane = tid & 63, l16 = lane & 15, quad = lane >> 4;
    bool diag = (ti == tj);
    float step = stepp[0], decay = decayp[0];

    // zero Lbuf+Rbuf (contiguous: 40960+32768 = 73728 floats), agent-scope stores
    for (int i = bid * 256 + tid; i < 73728; i += NBLK * 256) astore(&Lbuf[i], 0.f);
    if (tid < 128) chRn[tid] = charge0[b * 2048 + ti * 128 + tid];
    else chCn[tid - 128] = charge0[b * 2048 + tj * 128 + (tid - 128)];

    // ---- compat tile via MFMA, kept in registers (packed bf16)
    int rbase = b * 2048 + ti * 128 + wave * 32;
    int cbase = b * 2048 + tj * 128;
    unsigned cpk[2][8][2];
    {
        f32x4 acc[2][8] = {};
#pragma unroll
        for (int kc = 0; kc < 64; kc += 32) {
            int ko = kc + quad * 8;
            bf16x8 af[2], bfm[8];
#pragma unroll
            for (int f = 0; f < 2; f++)
                af[f] = *reinterpret_cast<const bf16x8*>(Qb + (long)(rbase + f * 16 + l16) * 64 + ko);
#pragma unroll
            for (int f = 0; f < 8; f++)
                bfm[f] = *reinterpret_cast<const bf16x8*>(Kb + (long)(cbase + f * 16 + l16) * 64 + ko);
#pragma unroll
            for (int i = 0; i < 2; i++)
#pragma unroll
                for (int j = 0; j < 8; j++)
                    acc[i][j] = __builtin_amdgcn_mfma_f32_16x16x32_bf16(af[i], bfm[j], acc[i][j], 0, 0, 0);
        }
#pragma unroll
        for (int i = 0; i < 2; i++)
#pragma unroll
            for (int j = 0; j < 8; j++) {
                cpk[i][j][0] = pk2(acc[i][j][0], acc[i][j][1]);
                cpk[i][j][1] = pk2(acc[i][j][2], acc[i][j][3]);
            }
    }
    float dot[2][8][4] = {};  // running sum_s c_s[n]*c_s[m] per owned (row,col) pair

    // local charge update from completed Rbuf[t-1], then fold into running dot
    auto upd = [&](int t) {
        const float* Rp = Rbuf + (long)(t - 1) * 8192 + b * 2048;
        if (tid < 128) chRn[tid] *= (1.f - decay * sigm(aload(&Rp[ti * 128 + tid]) - 1.f));
        else { int m = tid - 128; chCn[m] *= (1.f - decay * sigm(aload(&Rp[tj * 128 + m]) - 1.f)); }
        __syncthreads();
        float rv[2][4], cv[8];
#pragma unroll
        for (int i = 0; i < 2; i++)
#pragma unroll
            for (int rr = 0; rr < 4; rr++) rv[i][rr] = chRn[wave * 32 + i * 16 + quad * 4 + rr];
#pragma unroll
        for (int j = 0; j < 8; j++) cv[j] = chCn[j * 16 + l16];
#pragma unroll
        for (int i = 0; i < 2; i++)
#pragma unroll
            for (int j = 0; j < 8; j++)
#pragma unroll
                for (int rr = 0; rr < 4; rr++) dot[i][j][rr] += rv[i][rr] * cv[j];
    };

    // reduce row-sums across the 16-lane group and push coherent atomics
    auto rowred = [&](float (&S)[2][4], float* Lt) {
#pragma unroll
        for (int i = 0; i < 2; i++)
#pragma unroll
            for (int rr = 0; rr < 4; rr++) {
                float s = S[i][rr];
                s += __shfl_xor(s, 1); s += __shfl_xor(s, 2);
                s += __shfl_xor(s, 4); s += __shfl_xor(s, 8);
                S[i][rr] = s;
            }
#pragma unroll
        for (int e = 0; e < 8; e++) {
            int i = e >> 2, rr = e & 3;
            if (l16 == e) afadd(&Lt[i * 16 + quad * 4 + rr], S[i][rr]);
        }
    };

    int ord = 0;
    gbar(bar, ++ord);  // (1) zero visible everywhere

    for (int t = 0; t < 4; ++t) {
        if (t > 0) upd(t);
        // ---- row pass: partial L[n]
        float S[2][4] = {};
#pragma unroll
        for (int i = 0; i < 2; i++)
#pragma unroll
            for (int rr = 0; rr < 4; rr++) {
                int rl = wave * 32 + i * 16 + quad * 4 + rr;
                float s = 0.f;
#pragma unroll
                for (int j = 0; j < 8; j++) {
                    float c = upk(cpk[i][j][rr >> 1], rr & 1);
                    float sg = fmaf(step, dot[i][j][rr], 1.f);
                    float p = __expf(c * sg);
                    if (diag && (j * 16 + l16) > rl) p = 0.f;
                    s += p;
                }
                S[i][rr] = s;
            }
        rowred(S, Lbuf + (long)t * 8192 + b * 2048 + ti * 128 + wave * 32);
        gbar(bar, ++ord);

        // ---- col pass: received[m] += sum_n p/L[n]
        if (tid < 128) {
            LiL[tid] = 1.f / fmaxf(aload(&Lbuf[(long)t * 8192 + b * 2048 + ti * 128 + tid]), 1e-30f);
            colacc[tid] = 0.f;
        }
        __syncthreads();
        float colS[8] = {};
#pragma unroll
        for (int i = 0; i < 2; i++)
#pragma unroll
            for (int rr = 0; rr < 4; rr++) {
                int rl = wave * 32 + i * 16 + quad * 4 + rr;
                float li = LiL[rl];
#pragma unroll
                for (int j = 0; j < 8; j++) {
                    float c = upk(cpk[i][j][rr >> 1], rr & 1);
                    float sg = fmaf(step, dot[i][j][rr], 1.f);
                    float p = __expf(c * sg) * li;
                    if (diag && (j * 16 + l16) > rl) p = 0.f;
                    colS[j] += p;
                }
            }
#pragma unroll
        for (int j = 0; j < 8; j++) {
            float s = colS[j];
            s += __shfl_xor(s, 16); s += __shfl_xor(s, 32);
            if (quad == 0) atomicAdd(&colacc[j * 16 + l16], s);
        }
        __syncthreads();
        if (tid < 128) afadd(&Rbuf[(long)t * 8192 + b * 2048 + tj * 128 + tid], colacc[tid]);
        gbar(bar, ++ord);
    }

    // ---- final: charge_4, p with sg_4, L4 row sums, PV MFMA, partial slab write
    upd(4);
    {
        float S[2][4] = {};
#pragma unroll
        for (int i = 0; i < 2; i++)
#pragma unroll
            for (int rr = 0; rr < 4; rr++) {
                int rl = wave * 32 + i * 16 + quad * 4 + rr;
                float s = 0.f;
#pragma unroll
                for (int j = 0; j < 8; j++) {
                    float c = upk(cpk[i][j][rr >> 1], rr & 1);
                    float sg = fmaf(step, dot[i][j][rr], 1.f);
                    float p = __expf(c * sg);
                    if (diag && (j * 16 + l16) > rl) p = 0.f;
                    s += p;
                    pstage[wave][i * 16 + quad * 4 + rr][j * 16 + l16] = (ushort_t)f2bf(p);
                }
                S[i][rr] = s;
            }
        rowred(S, Lbuf + 4L * 8192 + b * 2048 + ti * 128 + wave * 32);
    }
    __syncthreads();
    {
        f32x4 po[2][4] = {};
#pragma unroll
        for (int kc4 = 0; kc4 < 4; kc4++) {
            int mk = kc4 * 32 + quad * 8;
            bf16x8 pa[2], vf[4];
#pragma unroll
            for (int i = 0; i < 2; i++)
                pa[i] = *reinterpret_cast<const bf16x8*>(&pstage[wave][i * 16 + l16][mk]);
#pragma unroll
            for (int f = 0; f < 4; f++)
                vf[f] = *reinterpret_cast<const bf16x8*>(VbT + (long)(f * 16 + l16) * 8192 + cbase + mk);
#pragma unroll
            for (int i = 0; i < 2; i++)
#pragma unroll
                for (int f = 0; f < 4; f++)
                    po[i][f] = __builtin_amdgcn_mfma_f32_16x16x32_bf16(pa[i], vf[f], po[i][f], 0, 0, 0);
        }
        float* Op = Opart + (long)bid * (128 * 64);
#pragma unroll
        for (int i = 0; i < 2; i++)
#pragma unroll
            for (int f = 0; f < 4; f++)
#pragma unroll
                for (int rr = 0; rr < 4; rr++)
                    Op[(wave * 32 + i * 16 + quad * 4 + rr) * 64 + f * 16 + l16] = po[i][f][rr];
    }
}

// ---------------- reduce PV partials across tj tiles, normalize by 1/L4, emit bf16 A
__global__ __launch_bounds__(256) void k_reduce(const float* __restrict__ Opart,
        const float* __restrict__ L4, ushort_t* __restrict__ Abf) {
    int bid = blockIdx.x;            // 512 blocks, 16 rows each
    int g0 = bid * 16;
    int b = g0 >> 11;                // /2048
    int loc = g0 & 2047;
    int ti = loc >> 7;               // /128
    int rloc0 = loc & 127;
    int tri = ti * (ti + 1) / 2;
    int row_off = threadIdx.x >> 4;  // 0..15
    int c0 = (threadIdx.x & 15) * 4; // 4 cols
    int rloc = rloc0 + row_off;
    int n = g0 + row_off;
    float4 s = {0.f, 0.f, 0.f, 0.f};
    for (int tj = 0; tj <= ti; tj++) {
        const float4 v = *reinterpret_cast<const float4*>(
            Opart + ((long)((tri + tj) * 4 + b) * 128 + rloc) * 64 + c0);
        s.x += v.x; s.y += v.y; s.z += v.z; s.w += v.w;
    }
    float inv = 1.f / fmaxf(L4[n], 1e-30f);
    u16x4 o;
    o[0] = (ushort_t)f2bf(s.x * inv);
    o[1] = (ushort_t)f2bf(s.y * inv);
    o[2] = (ushort_t)f2bf(s.z * inv);
    o[3] = (ushort_t)f2bf(s.w * inv);
    *reinterpret_cast<u16x4*>(Abf + (long)n * 64 + c0) = o;
}

// ---------------- out = (Abf @ Wo^T) * 0.1, fp32 store
__global__ __launch_bounds__(256) void k_oproj(const ushort_t* __restrict__ Abf,
                                               const float* __restrict__ Wo,
                                               float* __restrict__ out) {
    int mt = blockIdx.x & 63, nt = blockIdx.x >> 6;
    int wave = threadIdx.x >> 6, lane = threadIdx.x & 63;
    int wm = wave >> 1, wn = wave & 1;
    int l16 = lane & 15, quad = lane >> 4;
    int row0 = mt * 128 + wm * 64;
    int col0 = nt * 128 + wn * 64;
    f32x4 acc[4][4] = {};
#pragma unroll
    for (int kc = 0; kc < 64; kc += 32) {
        int ko = kc + quad * 8;
        bf16x8 af[4], bfm[4];
#pragma unroll
        for (int f = 0; f < 4; f++)
            af[f] = *reinterpret_cast<const bf16x8*>(Abf + (long)(row0 + f * 16 + l16) * 64 + ko);
#pragma unroll
        for (int f = 0; f < 4; f++) bfm[f] = ld8f(Wo + (long)(col0 + f * 16 + l16) * 64 + ko);
#pragma unroll
        for (int i = 0; i < 4; i++)
#pragma unroll
            for (int j = 0; j < 4; j++)
                acc[i][j] = __builtin_amdgcn_mfma_f32_16x16x32_bf16(af[i], bfm[j], acc[i][j], 0, 0, 0);
    }
#pragma unroll
    for (int i = 0; i < 4; i++)
#pragma unroll
        for (int j = 0; j < 4; j++)
#pragma unroll
            for (int rr = 0; rr < 4; rr++) {
                long rowg = row0 + i * 16 + quad * 4 + rr;
                int colg = col0 + j * 16 + l16;
                out[rowg * 1024 + colg] = acc[i][j][rr] * 0.1f;
            }
}

extern "C" void kernel_launch(void* const* d_in, const int* in_sizes, int n_in,
                              void* d_out, int out_size, void* d_ws, size_t ws_size,
                              hipStream_t stream) {
    const float* hidden = (const float*)d_in[0];
    const float* W1 = (const float*)d_in[1];
    const float* b1 = (const float*)d_in[2];
    const float* W2 = (const float*)d_in[3];
    const float* b2 = (const float*)d_in[4];
    const float* Wq = (const float*)d_in[5];
    const float* Wk = (const float*)d_in[6];
    const float* Wc = (const float*)d_in[7];
    const float* bc = (const float*)d_in[8];
    const float* Wv = (const float*)d_in[9];
    const float* Wo = (const float*)d_in[10];
    const float* stepp = (const float*)d_in[11];
    const float* decayp = (const float*)d_in[12];

    char* ws = (char*)d_ws;
    size_t off = 0;
    auto alloc = [&](size_t bytes) {
        void* p = ws + off;
        off += (bytes + 255) & ~(size_t)255;
        return p;
    };
    ushort_t* Hb = (ushort_t*)alloc(8192UL * 1024 * 2);   // 16 MiB bf16 hidden
    ushort_t* Wcat = (ushort_t*)alloc(128UL * 1024 * 2);  // W1;Wv bf16
    float* Ff = (float*)alloc(8192UL * 64 * 4);           // 2 MiB
    ushort_t* Qb = (ushort_t*)alloc(8192UL * 64 * 2);
    ushort_t* Kb = (ushort_t*)alloc(8192UL * 64 * 2);
    ushort_t* VbT = (ushort_t*)alloc(64UL * 8192 * 2);
    float* charge0 = (float*)alloc(8192UL * 4);
    // Lbuf and Rbuf MUST stay contiguous (k_fused zeroes them as one range):
    float* Lbuf = (float*)alloc(5UL * 8192 * 4);   // 160 KiB (40960 floats)
    float* Rbuf = (float*)alloc(4UL * 8192 * 4);   // 128 KiB (32768 floats)
    float* Opart = (float*)alloc(544UL * 128 * 64 * 4);  // 17.8 MiB PV partials
    ushort_t* Abf = (ushort_t*)alloc(8192UL * 64 * 2);   // 1 MiB normalized A (bf16)
    int* bar = (int*)alloc(9728 * 4);              // padded barrier counters + flags
    (void)ws_size; (void)in_sizes; (void)n_in; (void)out_size;

    k_cvt<<<4160, 256, 0, stream>>>(hidden, W1, Wv, Hb, Wcat, bar);
    k_fv<<<512, 256, 0, stream>>>(Hb, Wcat, Ff, VbT);
    k_feat<<<256, 256, 0, stream>>>(Ff, b1, W2, b2, Wq, Wk, Wc, bc, Qb, Kb, charge0);
    k_fused<<<NBLK, 256, 0, stream>>>(Qb, Kb, VbT, charge0, stepp, decayp,
                                      Lbuf, Rbuf, Opart, bar);
    k_reduce<<<512, 256, 0, stream>>>(Opart, Lbuf + 4L * 8192, Abf);
    k_oproj<<<512, 256, 0, stream>>>(Abf, Wo, (float*)d_out);
}

// Round 5
// 767.699 us; speedup vs baseline: 1.1194x; 1.0016x over previous
//
#include <hip/hip_runtime.h>
#include <hip/hip_bf16.h>

typedef unsigned short ushort_t;
typedef short bf16x8 __attribute__((ext_vector_type(8)));
typedef ushort_t u16x8 __attribute__((ext_vector_type(8)));
typedef ushort_t u16x4 __attribute__((ext_vector_type(4)));
typedef float f32x4 __attribute__((ext_vector_type(4)));

#define DEV static __device__ __forceinline__
#define SCOPE_AGENT __HIP_MEMORY_SCOPE_AGENT
#define NBLK 544

DEV float bf2f(ushort_t u) { unsigned v = ((unsigned)u) << 16; float f; __builtin_memcpy(&f, &v, 4); return f; }
DEV short f2bf(float x) { __hip_bfloat16 h = __float2bfloat16(x); short s; __builtin_memcpy(&s, &h, 2); return s; }
DEV float sigm(float x) { return 1.0f / (1.0f + __expf(-x)); }
DEV unsigned pk2(float a, float b) {
    return ((unsigned)(ushort_t)f2bf(a)) | (((unsigned)(ushort_t)f2bf(b)) << 16);
}
DEV float upk(unsigned u, int hi) { return bf2f((ushort_t)(hi ? (u >> 16) : (u & 0xffffu))); }

// agent-scope coherent helpers (correct across XCD L2s)
DEV float aload(const float* p) { return __hip_atomic_load((float*)p, __ATOMIC_RELAXED, SCOPE_AGENT); }
DEV void astore(float* p, float v) { __hip_atomic_store(p, v, __ATOMIC_RELAXED, SCOPE_AGENT); }
DEV void afadd(float* p, float v) { __hip_atomic_fetch_add(p, v, __ATOMIC_RELAXED, SCOPE_AGENT); }

DEV bf16x8 cvt8(float4 a0, float4 a1) {
    bf16x8 t;
    t[0] = f2bf(a0.x); t[1] = f2bf(a0.y); t[2] = f2bf(a0.z); t[3] = f2bf(a0.w);
    t[4] = f2bf(a1.x); t[5] = f2bf(a1.y); t[6] = f2bf(a1.z); t[7] = f2bf(a1.w);
    return t;
}
DEV bf16x8 ld8f(const float* __restrict__ p) {
    return cvt8(*reinterpret_cast<const float4*>(p), *reinterpret_cast<const float4*>(p + 4));
}

// grid barrier, contention-free:
//  - 32 arrival counters, each on its own 128B line (17 blocks/counter)
//  - block 0 polls the 32 counters (1 thread each), then releases via per-block
//    flags each on a private 64B line; every block spins on its OWN flag only.
// bar layout (ints): arrive[s] at bar[s*32] (s<32); relflag[b] at bar[1024+b*16].
// Total 9728 ints, re-zeroed by k_cvt each launch (graph replay safe).
DEV void gbar(int* bar, int ord) {
    __syncthreads();
    if (threadIdx.x == 0)
        __hip_atomic_fetch_add(&bar[(blockIdx.x & 31) * 32], 1, __ATOMIC_ACQ_REL, SCOPE_AGENT);
    if (blockIdx.x == 0) {
        if (threadIdx.x < 32)
            while (__hip_atomic_load(&bar[threadIdx.x * 32], __ATOMIC_ACQUIRE, SCOPE_AGENT) < ord * (NBLK / 32))
                __builtin_amdgcn_s_sleep(2);
        __syncthreads();
        for (int i = threadIdx.x; i < NBLK; i += 256)
            __hip_atomic_store(&bar[1024 + i * 16], ord, __ATOMIC_RELEASE, SCOPE_AGENT);
    }
    if (threadIdx.x == 0)
        while (__hip_atomic_load(&bar[1024 + blockIdx.x * 16], __ATOMIC_ACQUIRE, SCOPE_AGENT) < ord)
            __builtin_amdgcn_s_sleep(2);
    __syncthreads();
}

// ---------------- K0: fp32 -> bf16 for hidden, W1, Wv; also re-arm barrier region
__global__ void k_cvt(const float* __restrict__ h, const float* __restrict__ W1,
                      const float* __restrict__ Wv, ushort_t* __restrict__ Hb,
                      ushort_t* __restrict__ Wcat, int* __restrict__ bar) {
    long i = (long)blockIdx.x * 256 + threadIdx.x;
    if (i < 9728) bar[i] = 0;
    const float* src;
    ushort_t* dst;
    if (i < 1048576) { src = h + i * 8; dst = Hb + i * 8; }
    else if (i < 1056768) { long j = i - 1048576; src = W1 + j * 8; dst = Wcat + j * 8; }
    else { long j = i - 1056768; src = Wv + j * 8; dst = Wcat + 65536 + j * 8; }
    const float4* p = reinterpret_cast<const float4*>(src);
    *reinterpret_cast<bf16x8*>(dst) = cvt8(p[0], p[1]);
}

// ---------------- K1: Ff[8192][64] = Hb@W1^T (fp32), VbT[64][8192] = (Hb@Wv^T)^T bf16
__global__ __launch_bounds__(256) void k_fv(const ushort_t* __restrict__ Hb,
        const ushort_t* __restrict__ Wcat,
        float* __restrict__ Ff, ushort_t* __restrict__ VbT) {
    int m0 = blockIdx.x * 16;
    int wave = threadIdx.x >> 6, lane = threadIdx.x & 63;
    int l16 = lane & 15, quad = lane >> 4;
    int cb = (wave & 1) * 32;
    int brow_off = (wave < 2) ? 0 : 64;   // rows 0-63 = W1, 64-127 = Wv
    f32x4 acc[2] = {};
    const ushort_t* arow = Hb + (long)(m0 + l16) * 1024;
    const ushort_t* brow0 = Wcat + (long)(brow_off + cb + l16) * 1024;
    const ushort_t* brow1 = Wcat + (long)(brow_off + cb + 16 + l16) * 1024;
    for (int kc = 0; kc < 1024; kc += 128) {
        bf16x8 a4[4], b04[4], b14[4];
#pragma unroll
        for (int u = 0; u < 4; u++) {
            int ko = kc + u * 32 + quad * 8;
            a4[u] = *reinterpret_cast<const bf16x8*>(arow + ko);
            b04[u] = *reinterpret_cast<const bf16x8*>(brow0 + ko);
            b14[u] = *reinterpret_cast<const bf16x8*>(brow1 + ko);
        }
#pragma unroll
        for (int u = 0; u < 4; u++) {
            acc[0] = __builtin_amdgcn_mfma_f32_16x16x32_bf16(a4[u], b04[u], acc[0], 0, 0, 0);
            acc[1] = __builtin_amdgcn_mfma_f32_16x16x32_bf16(a4[u], b14[u], acc[1], 0, 0, 0);
        }
    }
    bool isV = (wave >= 2);
#pragma unroll
    for (int c = 0; c < 2; c++)
#pragma unroll
        for (int rr = 0; rr < 4; rr++) {
            int row = m0 + quad * 4 + rr;
            int col = cb + c * 16 + l16;
            float v = acc[c][rr];
            if (!isV) Ff[row * 64 + col] = v;
            else VbT[(long)col * 8192 + row] = (ushort_t)f2bf(v);
        }
}

// ---------------- K2: gelu -> features -> Q,K,charge0. 256 blocks x 32 rows.
__global__ __launch_bounds__(256) void k_feat(const float* __restrict__ Ff,
        const float* __restrict__ b1, const float* __restrict__ W2, const float* __restrict__ b2,
        const float* __restrict__ Wq, const float* __restrict__ Wk,
        const float* __restrict__ Wc, const float* __restrict__ bc,
        ushort_t* __restrict__ Qb, ushort_t* __restrict__ Kb,
        float* __restrict__ charge0) {
    __shared__ float w2L[28 * 65], wqL[64 * 29], wkL[64 * 29], wcL[28], b2L[28];
    __shared__ float fL[4][64], featL[4][28];
    int tid = threadIdx.x;
    for (int i = tid; i < 28 * 64; i += 256) w2L[(i >> 6) * 65 + (i & 63)] = W2[i];
    for (int i = tid; i < 64 * 28; i += 256) {
        int r = i / 28, c = i - r * 28;
        wqL[r * 29 + c] = Wq[i];
        wkL[r * 29 + c] = Wk[i];
    }
    if (tid < 28) { wcL[tid] = Wc[tid]; b2L[tid] = b2[tid]; }
    __syncthreads();
    int w = tid >> 6, lane = tid & 63;
    float b1v = b1[lane];
    float bcv = bc[0];
    for (int it = 0; it < 8; it++) {
        int row = blockIdx.x * 32 + it * 4 + w;
        float x = Ff[row * 64 + lane] + b1v;
        fL[w][lane] = 0.5f * x * (1.0f + erff(x * 0.70710678118654752f));
        __syncthreads();
        if (lane < 28) {
            float s = b2L[lane];
#pragma unroll
            for (int j = 0; j < 64; j++) s += fL[w][j] * w2L[lane * 65 + j];
            featL[w][lane] = sigm(s);
        }
        __syncthreads();
        float q = 0.f, k = 0.f;
#pragma unroll
        for (int i = 0; i < 28; i++) {
            float fv = featL[w][i];
            q += fv * wqL[lane * 29 + i];
            k += fv * wkL[lane * 29 + i];
        }
        Qb[row * 64 + lane] = (ushort_t)f2bf(q * 0.125f);  // fold 1/sqrt(64)
        Kb[row * 64 + lane] = (ushort_t)f2bf(k);
        if (lane == 0) {
            float c = bcv;
#pragma unroll
            for (int i = 0; i < 28; i++) c += featL[w][i] * wcL[i];
            charge0[row] = sigm(c);
        }
        __syncthreads();
    }
}

DEV void tri_decode(int r, int& ti, int& tj) {
    int t = (int)((sqrtf(8.f * (float)r + 1.f) - 1.f) * 0.5f);
    while ((t + 1) * (t + 2) / 2 <= r) t++;
    while (t * (t + 1) / 2 > r) t--;
    ti = t;
    tj = r - t * (t + 1) / 2;
}

// ---------------- FUSED persistent kernel: compat MFMA (regs) + 4x(rowsum, colsum,
// local charge update) + final PV, with 9 contention-free grid barriers.
// Grid MUST be 544 = 4 batches x 136 causal 128x128 tiles.
// Per-thread live state across barriers: cpk(32) + dot(64) = 96 VGPRs.
// amdgpu_waves_per_eu(3,3) pins the allocator budget to ~168 VGPR so the
// occupancy heuristic cannot target 6 waves/EU (=84 regs) and spill ~40
// regs/thread to scratch (that spill was the round-3 90MB FETCH / 75MB WRITE).
// Worst-case residency: 3 waves/EU -> 3 blocks/CU -> 768 >= 544, no deadlock.
__global__ void __launch_bounds__(256) __attribute__((amdgpu_waves_per_eu(3, 3))) k_fused(
        const ushort_t* __restrict__ Qb, const ushort_t* __restrict__ Kb,
        const ushort_t* __restrict__ VbT, const float* __restrict__ charge0,
        const float* __restrict__ stepp, const float* __restrict__ decayp,
        float* __restrict__ Lbuf,    // [5][8192] row softmax denominators per stage
        float* __restrict__ Rbuf,    // [4][8192] received per iteration (contiguous after Lbuf)
        float* __restrict__ Opart,   // [544][128][64] per-tile PV partials
        int* bar) {
    __shared__ float chRn[128], chCn[128];   // current charge, tile rows / cols
    __shared__ float LiL[128], colacc[128];
    __shared__ __align__(16) ushort_t pstage[4][32][136];  // final-phase p (per wave), padded

    int bid = blockIdx.x, tid = threadIdx.x;
    int b = bid & 3, r = bid >> 2, ti, tj;
    tri_decode(r, ti, tj);
    int wave = tid >> 6, lane = tid & 63, l16 = lane & 15, quad = lane >> 4;
    bool diag = (ti == tj);
    float step = stepp[0], decay = decayp[0];

    // zero Lbuf+Rbuf (contiguous: 40960+32768 = 73728 floats), agent-scope stores
    for (int i = bid * 256 + tid; i < 73728; i += NBLK * 256) astore(&Lbuf[i], 0.f);
    if (tid < 128) chRn[tid] = charge0[b * 2048 + ti * 128 + tid];
    else chCn[tid - 128] = charge0[b * 2048 + tj * 128 + (tid - 128)];

    // ---- compat tile via MFMA, kept in registers (packed bf16)
    int rbase = b * 2048 + ti * 128 + wave * 32;
    int cbase = b * 2048 + tj * 128;
    unsigned cpk[2][8][2];
    {
        f32x4 acc[2][8] = {};
#pragma unroll
        for (int kc = 0; kc < 64; kc += 32) {
            int ko = kc + quad * 8;
            bf16x8 af[2], bfm[8];
#pragma unroll
            for (int f = 0; f < 2; f++)
                af[f] = *reinterpret_cast<const bf16x8*>(Qb + (long)(rbase + f * 16 + l16) * 64 + ko);
#pragma unroll
            for (int f = 0; f < 8; f++)
                bfm[f] = *reinterpret_cast<const bf16x8*>(Kb + (long)(cbase + f * 16 + l16) * 64 + ko);
#pragma unroll
            for (int i = 0; i < 2; i++)
#pragma unroll
                for (int j = 0; j < 8; j++)
                    acc[i][j] = __builtin_amdgcn_mfma_f32_16x16x32_bf16(af[i], bfm[j], acc[i][j], 0, 0, 0);
        }
#pragma unroll
        for (int i = 0; i < 2; i++)
#pragma unroll
            for (int j = 0; j < 8; j++) {
                cpk[i][j][0] = pk2(acc[i][j][0], acc[i][j][1]);
                cpk[i][j][1] = pk2(acc[i][j][2], acc[i][j][3]);
            }
    }
    float dot[2][8][4] = {};  // running sum_s c_s[n]*c_s[m] per owned (row,col) pair

    // local charge update from completed Rbuf[t-1], then fold into running dot
    auto upd = [&](int t) {
        const float* Rp = Rbuf + (long)(t - 1) * 8192 + b * 2048;
        if (tid < 128) chRn[tid] *= (1.f - decay * sigm(aload(&Rp[ti * 128 + tid]) - 1.f));
        else { int m = tid - 128; chCn[m] *= (1.f - decay * sigm(aload(&Rp[tj * 128 + m]) - 1.f)); }
        __syncthreads();
        float rv[2][4], cv[8];
#pragma unroll
        for (int i = 0; i < 2; i++)
#pragma unroll
            for (int rr = 0; rr < 4; rr++) rv[i][rr] = chRn[wave * 32 + i * 16 + quad * 4 + rr];
#pragma unroll
        for (int j = 0; j < 8; j++) cv[j] = chCn[j * 16 + l16];
#pragma unroll
        for (int i = 0; i < 2; i++)
#pragma unroll
            for (int j = 0; j < 8; j++)
#pragma unroll
                for (int rr = 0; rr < 4; rr++) dot[i][j][rr] += rv[i][rr] * cv[j];
    };

    // reduce row-sums across the 16-lane group and push coherent atomics
    auto rowred = [&](float (&S)[2][4], float* Lt) {
#pragma unroll
        for (int i = 0; i < 2; i++)
#pragma unroll
            for (int rr = 0; rr < 4; rr++) {
                float s = S[i][rr];
                s += __shfl_xor(s, 1); s += __shfl_xor(s, 2);
                s += __shfl_xor(s, 4); s += __shfl_xor(s, 8);
                S[i][rr] = s;
            }
#pragma unroll
        for (int e = 0; e < 8; e++) {
            int i = e >> 2, rr = e & 3;
            if (l16 == e) afadd(&Lt[i * 16 + quad * 4 + rr], S[i][rr]);
        }
    };

    int ord = 0;
    gbar(bar, ++ord);  // (1) zero visible everywhere

    for (int t = 0; t < 4; ++t) {
        if (t > 0) upd(t);
        // ---- row pass: partial L[n]
        float S[2][4] = {};
#pragma unroll
        for (int i = 0; i < 2; i++)
#pragma unroll
            for (int rr = 0; rr < 4; rr++) {
                int rl = wave * 32 + i * 16 + quad * 4 + rr;
                float s = 0.f;
#pragma unroll
                for (int j = 0; j < 8; j++) {
                    float c = upk(cpk[i][j][rr >> 1], rr & 1);
                    float sg = fmaf(step, dot[i][j][rr], 1.f);
                    float p = __expf(c * sg);
                    if (diag && (j * 16 + l16) > rl) p = 0.f;
                    s += p;
                }
                S[i][rr] = s;
            }
        rowred(S, Lbuf + (long)t * 8192 + b * 2048 + ti * 128 + wave * 32);
        gbar(bar, ++ord);

        // ---- col pass: received[m] += sum_n p/L[n]
        if (tid < 128) {
            LiL[tid] = 1.f / fmaxf(aload(&Lbuf[(long)t * 8192 + b * 2048 + ti * 128 + tid]), 1e-30f);
            colacc[tid] = 0.f;
        }
        __syncthreads();
        float colS[8] = {};
#pragma unroll
        for (int i = 0; i < 2; i++)
#pragma unroll
            for (int rr = 0; rr < 4; rr++) {
                int rl = wave * 32 + i * 16 + quad * 4 + rr;
                float li = LiL[rl];
#pragma unroll
                for (int j = 0; j < 8; j++) {
                    float c = upk(cpk[i][j][rr >> 1], rr & 1);
                    float sg = fmaf(step, dot[i][j][rr], 1.f);
                    float p = __expf(c * sg) * li;
                    if (diag && (j * 16 + l16) > rl) p = 0.f;
                    colS[j] += p;
                }
            }
#pragma unroll
        for (int j = 0; j < 8; j++) {
            float s = colS[j];
            s += __shfl_xor(s, 16); s += __shfl_xor(s, 32);
            if (quad == 0) atomicAdd(&colacc[j * 16 + l16], s);
        }
        __syncthreads();
        if (tid < 128) afadd(&Rbuf[(long)t * 8192 + b * 2048 + tj * 128 + tid], colacc[tid]);
        gbar(bar, ++ord);
    }

    // ---- final: charge_4, p with sg_4, L4 row sums, PV MFMA, partial slab write
    upd(4);
    {
        float S[2][4] = {};
#pragma unroll
        for (int i = 0; i < 2; i++)
#pragma unroll
            for (int rr = 0; rr < 4; rr++) {
                int rl = wave * 32 + i * 16 + quad * 4 + rr;
                float s = 0.f;
#pragma unroll
                for (int j = 0; j < 8; j++) {
                    float c = upk(cpk[i][j][rr >> 1], rr & 1);
                    float sg = fmaf(step, dot[i][j][rr], 1.f);
                    float p = __expf(c * sg);
                    if (diag && (j * 16 + l16) > rl) p = 0.f;
                    s += p;
                    pstage[wave][i * 16 + quad * 4 + rr][j * 16 + l16] = (ushort_t)f2bf(p);
                }
                S[i][rr] = s;
            }
        rowred(S, Lbuf + 4L * 8192 + b * 2048 + ti * 128 + wave * 32);
    }
    __syncthreads();
    {
        f32x4 po[2][4] = {};
#pragma unroll
        for (int kc4 = 0; kc4 < 4; kc4++) {
            int mk = kc4 * 32 + quad * 8;
            bf16x8 pa[2], vf[4];
#pragma unroll
            for (int i = 0; i < 2; i++)
                pa[i] = *reinterpret_cast<const bf16x8*>(&pstage[wave][i * 16 + l16][mk]);
#pragma unroll
            for (int f = 0; f < 4; f++)
                vf[f] = *reinterpret_cast<const bf16x8*>(VbT + (long)(f * 16 + l16) * 8192 + cbase + mk);
#pragma unroll
            for (int i = 0; i < 2; i++)
#pragma unroll
                for (int f = 0; f < 4; f++)
                    po[i][f] = __builtin_amdgcn_mfma_f32_16x16x32_bf16(pa[i], vf[f], po[i][f], 0, 0, 0);
        }
        float* Op = Opart + (long)bid * (128 * 64);
#pragma unroll
        for (int i = 0; i < 2; i++)
#pragma unroll
            for (int f = 0; f < 4; f++)
#pragma unroll
                for (int rr = 0; rr < 4; rr++)
                    Op[(wave * 32 + i * 16 + quad * 4 + rr) * 64 + f * 16 + l16] = po[i][f][rr];
    }
}

// ---------------- reduce PV partials across tj tiles, normalize by 1/L4, emit bf16 A
__global__ __launch_bounds__(256) void k_reduce(const float* __restrict__ Opart,
        const float* __restrict__ L4, ushort_t* __restrict__ Abf) {
    int bid = blockIdx.x;            // 512 blocks, 16 rows each
    int g0 = bid * 16;
    int b = g0 >> 11;                // /2048
    int loc = g0 & 2047;
    int ti = loc >> 7;               // /128
    int rloc0 = loc & 127;
    int tri = ti * (ti + 1) / 2;
    int row_off = threadIdx.x >> 4;  // 0..15
    int c0 = (threadIdx.x & 15) * 4; // 4 cols
    int rloc = rloc0 + row_off;
    int n = g0 + row_off;
    float4 s = {0.f, 0.f, 0.f, 0.f};
    for (int tj = 0; tj <= ti; tj++) {
        const float4 v = *reinterpret_cast<const float4*>(
            Opart + ((long)((tri + tj) * 4 + b) * 128 + rloc) * 64 + c0);
        s.x += v.x; s.y += v.y; s.z += v.z; s.w += v.w;
    }
    float inv = 1.f / fmaxf(L4[n], 1e-30f);
    u16x4 o;
    o[0] = (ushort_t)f2bf(s.x * inv);
    o[1] = (ushort_t)f2bf(s.y * inv);
    o[2] = (ushort_t)f2bf(s.z * inv);
    o[3] = (ushort_t)f2bf(s.w * inv);
    *reinterpret_cast<u16x4*>(Abf + (long)n * 64 + c0) = o;
}

// ---------------- out = (Abf @ Wo^T) * 0.1, fp32 store
__global__ __launch_bounds__(256) void k_oproj(const ushort_t* __restrict__ Abf,
                                               const float* __restrict__ Wo,
                                               float* __restrict__ out) {
    int mt = blockIdx.x & 63, nt = blockIdx.x >> 6;
    int wave = threadIdx.x >> 6, lane = threadIdx.x & 63;
    int wm = wave >> 1, wn = wave & 1;
    int l16 = lane & 15, quad = lane >> 4;
    int row0 = mt * 128 + wm * 64;
    int col0 = nt * 128 + wn * 64;
    f32x4 acc[4][4] = {};
#pragma unroll
    for (int kc = 0; kc < 64; kc += 32) {
        int ko = kc + quad * 8;
        bf16x8 af[4], bfm[4];
#pragma unroll
        for (int f = 0; f < 4; f++)
            af[f] = *reinterpret_cast<const bf16x8*>(Abf + (long)(row0 + f * 16 + l16) * 64 + ko);
#pragma unroll
        for (int f = 0; f < 4; f++) bfm[f] = ld8f(Wo + (long)(col0 + f * 16 + l16) * 64 + ko);
#pragma unroll
        for (int i = 0; i < 4; i++)
#pragma unroll
            for (int j = 0; j < 4; j++)
                acc[i][j] = __builtin_amdgcn_mfma_f32_16x16x32_bf16(af[i], bfm[j], acc[i][j], 0, 0, 0);
    }
#pragma unroll
    for (int i = 0; i < 4; i++)
#pragma unroll
        for (int j = 0; j < 4; j++)
#pragma unroll
            for (int rr = 0; rr < 4; rr++) {
                long rowg = row0 + i * 16 + quad * 4 + rr;
                int colg = col0 + j * 16 + l16;
                out[rowg * 1024 + colg] = acc[i][j][rr] * 0.1f;
            }
}

extern "C" void kernel_launch(void* const* d_in, const int* in_sizes, int n_in,
                              void* d_out, int out_size, void* d_ws, size_t ws_size,
                              hipStream_t stream) {
    const float* hidden = (const float*)d_in[0];
    const float* W1 = (const float*)d_in[1];
    const float* b1 = (const float*)d_in[2];
    const float* W2 = (const float*)d_in[3];
    const float* b2 = (const float*)d_in[4];
    const float* Wq = (const float*)d_in[5];
    const float* Wk = (const float*)d_in[6];
    const float* Wc = (const float*)d_in[7];
    const float* bc = (const float*)d_in[8];
    const float* Wv = (const float*)d_in[9];
    const float* Wo = (const float*)d_in[10];
    const float* stepp = (const float*)d_in[11];
    const float* decayp = (const float*)d_in[12];

    char* ws = (char*)d_ws;
    size_t off = 0;
    auto alloc = [&](size_t bytes) {
        void* p = ws + off;
        off += (bytes + 255) & ~(size_t)255;
        return p;
    };
    ushort_t* Hb = (ushort_t*)alloc(8192UL * 1024 * 2);   // 16 MiB bf16 hidden
    ushort_t* Wcat = (ushort_t*)alloc(128UL * 1024 * 2);  // W1;Wv bf16
    float* Ff = (float*)alloc(8192UL * 64 * 4);           // 2 MiB
    ushort_t* Qb = (ushort_t*)alloc(8192UL * 64 * 2);
    ushort_t* Kb = (ushort_t*)alloc(8192UL * 64 * 2);
    ushort_t* VbT = (ushort_t*)alloc(64UL * 8192 * 2);
    float* charge0 = (float*)alloc(8192UL * 4);
    // Lbuf and Rbuf MUST stay contiguous (k_fused zeroes them as one range):
    float* Lbuf = (float*)alloc(5UL * 8192 * 4);   // 160 KiB (40960 floats)
    float* Rbuf = (float*)alloc(4UL * 8192 * 4);   // 128 KiB (32768 floats)
    float* Opart = (float*)alloc(544UL * 128 * 64 * 4);  // 17.8 MiB PV partials
    ushort_t* Abf = (ushort_t*)alloc(8192UL * 64 * 2);   // 1 MiB normalized A (bf16)
    int* bar = (int*)alloc(9728 * 4);              // padded barrier counters + flags
    (void)ws_size; (void)in_sizes; (void)n_in; (void)out_size;

    k_cvt<<<4160, 256, 0, stream>>>(hidden, W1, Wv, Hb, Wcat, bar);
    k_fv<<<512, 256, 0, stream>>>(Hb, Wcat, Ff, VbT);
    k_feat<<<256, 256, 0, stream>>>(Ff, b1, W2, b2, Wq, Wk, Wc, bc, Qb, Kb, charge0);
    k_fused<<<NBLK, 256, 0, stream>>>(Qb, Kb, VbT, charge0, stepp, decayp,
                                      Lbuf, Rbuf, Opart, bar);
    k_reduce<<<512, 256, 0, stream>>>(Opart, Lbuf + 4L * 8192, Abf);
    k_oproj<<<512, 256, 0, stream>>>(Abf, Wo, (float*)d_out);
}

// Round 6
// 379.898 us; speedup vs baseline: 2.2620x; 2.0208x over previous
//
#include <hip/hip_runtime.h>
#include <hip/hip_bf16.h>

typedef unsigned short ushort_t;
typedef short bf16x8 __attribute__((ext_vector_type(8)));
typedef ushort_t u16x8 __attribute__((ext_vector_type(8)));
typedef float f32x4 __attribute__((ext_vector_type(4)));

#define DEV static __device__ __forceinline__

DEV float bf2f(ushort_t u) { unsigned v = ((unsigned)u) << 16; float f; __builtin_memcpy(&f, &v, 4); return f; }
DEV short f2bf(float x) { __hip_bfloat16 h = __float2bfloat16(x); short s; __builtin_memcpy(&s, &h, 2); return s; }
DEV float sigm(float x) { return 1.0f / (1.0f + __expf(-x)); }
DEV unsigned pk2(float a, float b) {
    return ((unsigned)(ushort_t)f2bf(a)) | (((unsigned)(ushort_t)f2bf(b)) << 16);
}

DEV bf16x8 cvt8(float4 a0, float4 a1) {
    bf16x8 t;
    t[0] = f2bf(a0.x); t[1] = f2bf(a0.y); t[2] = f2bf(a0.z); t[3] = f2bf(a0.w);
    t[4] = f2bf(a1.x); t[5] = f2bf(a1.y); t[6] = f2bf(a1.z); t[7] = f2bf(a1.w);
    return t;
}
DEV bf16x8 ld8f(const float* __restrict__ p) {
    return cvt8(*reinterpret_cast<const float4*>(p), *reinterpret_cast<const float4*>(p + 4));
}

// ---------------- K0: fp32 -> bf16 for W1, Wv only (hidden consumed fp32 directly)
__global__ void k_cvtW(const float* __restrict__ W1, const float* __restrict__ Wv,
                       ushort_t* __restrict__ Wcat) {
    int i = blockIdx.x * 256 + threadIdx.x;  // 16384 threads, 8 elems each
    const float* src = (i < 8192) ? (W1 + (long)i * 8) : (Wv + (long)(i - 8192) * 8);
    const float4* p = reinterpret_cast<const float4*>(src);
    *reinterpret_cast<bf16x8*>(Wcat + (long)i * 8) = cvt8(p[0], p[1]);
}

// ---------------- K1: fused fv+feat. 512 blocks x 16 rows.
// waves 0-1: Ff = hidden@W1^T -> gelu -> LDS;  waves 2-3: VbT = (hidden@Wv^T)^T bf16.
// then feat chain (sigmoid(f@W2^T) -> Q,K,charge0) entirely from LDS.
__global__ __launch_bounds__(256) void k_fvfeat(const float* __restrict__ hidden,
        const ushort_t* __restrict__ Wcat, const float* __restrict__ b1,
        const float* __restrict__ W2, const float* __restrict__ b2,
        const float* __restrict__ Wq, const float* __restrict__ Wk,
        const float* __restrict__ Wc, const float* __restrict__ bc,
        ushort_t* __restrict__ Qb, ushort_t* __restrict__ Kb,
        ushort_t* __restrict__ VbT, float* __restrict__ charge0) {
    __shared__ float w2L[28 * 65], wqL[64 * 29], wkL[64 * 29], wcL[28], b2L[28];
    __shared__ float fLDS[16][65], featL[4][28];
    int tid = threadIdx.x;
    for (int i = tid; i < 28 * 64; i += 256) w2L[(i >> 6) * 65 + (i & 63)] = W2[i];
    for (int i = tid; i < 64 * 28; i += 256) {
        int r = i / 28, c = i - r * 28;
        wqL[r * 29 + c] = Wq[i];
        wkL[r * 29 + c] = Wk[i];
    }
    if (tid < 28) { wcL[tid] = Wc[tid]; b2L[tid] = b2[tid]; }

    int m0 = blockIdx.x * 16;
    int wave = tid >> 6, lane = tid & 63, l16 = lane & 15, quad = lane >> 4;
    int cb = (wave & 1) * 32;
    int brow_off = (wave < 2) ? 0 : 64;   // Wcat rows 0-63 = W1, 64-127 = Wv
    f32x4 acc[2] = {};
    const float* arow = hidden + (long)(m0 + l16) * 1024;
    const ushort_t* brow0 = Wcat + (long)(brow_off + cb + l16) * 1024;
    const ushort_t* brow1 = Wcat + (long)(brow_off + cb + 16 + l16) * 1024;
    for (int kc = 0; kc < 1024; kc += 128) {
#pragma unroll
        for (int u = 0; u < 4; u++) {
            int ko = kc + u * 32 + quad * 8;
            bf16x8 a = ld8f(arow + ko);
            bf16x8 b0 = *reinterpret_cast<const bf16x8*>(brow0 + ko);
            bf16x8 b1f = *reinterpret_cast<const bf16x8*>(brow1 + ko);
            acc[0] = __builtin_amdgcn_mfma_f32_16x16x32_bf16(a, b0, acc[0], 0, 0, 0);
            acc[1] = __builtin_amdgcn_mfma_f32_16x16x32_bf16(a, b1f, acc[1], 0, 0, 0);
        }
    }
    if (wave < 2) {
        float b1a = b1[cb + l16], b1b = b1[cb + 16 + l16];
#pragma unroll
        for (int c = 0; c < 2; c++) {
            float bv = c ? b1b : b1a;
#pragma unroll
            for (int rr = 0; rr < 4; rr++) {
                float x = acc[c][rr] + bv;
                fLDS[quad * 4 + rr][cb + c * 16 + l16] =
                    0.5f * x * (1.0f + erff(x * 0.70710678118654752f));
            }
        }
    } else {
#pragma unroll
        for (int c = 0; c < 2; c++)
#pragma unroll
            for (int rr = 0; rr < 4; rr++)
                VbT[(long)(cb + c * 16 + l16) * 8192 + (m0 + quad * 4 + rr)] =
                    (ushort_t)f2bf(acc[c][rr]);
    }
    __syncthreads();
    float bcv = bc[0];
    for (int it = 0; it < 4; it++) {
        int rowl = it * 4 + wave;
        int row = m0 + rowl;
        if (lane < 28) {
            float s = b2L[lane];
#pragma unroll
            for (int j = 0; j < 64; j++) s += fLDS[rowl][j] * w2L[lane * 65 + j];
            featL[wave][lane] = sigm(s);
        }
        __syncthreads();
        float q = 0.f, k = 0.f;
#pragma unroll
        for (int i = 0; i < 28; i++) {
            float fv = featL[wave][i];
            q += fv * wqL[lane * 29 + i];
            k += fv * wkL[lane * 29 + i];
        }
        Qb[row * 64 + lane] = (ushort_t)f2bf(q * 0.125f);  // fold 1/sqrt(64)
        Kb[row * 64 + lane] = (ushort_t)f2bf(k);
        if (lane == 0) {
            float c = bcv;
#pragma unroll
            for (int i = 0; i < 28; i++) c += featL[wave][i] * wcL[i];
            charge0[row] = sigm(c);
        }
        __syncthreads();
    }
}

DEV void tri_decode(int r, int& ti, int& tj) {
    int t = (int)((sqrtf(8.f * (float)r + 1.f) - 1.f) * 0.5f);
    while ((t + 1) * (t + 2) / 2 <= r) t++;
    while (t * (t + 1) / 2 > r) t--;
    ti = t;
    tj = r - t * (t + 1) / 2;
}

// ---------------- K2: compat[(b*2048+n)][m] = (Q/8)·K, causal 128x128 tiles, bf16
__global__ __launch_bounds__(256) void k_compat(const ushort_t* __restrict__ Qb,
                                                const ushort_t* __restrict__ Kb,
                                                ushort_t* __restrict__ compat) {
    int bid = blockIdx.x;
    int b = bid / 136, r = bid % 136, ti, tj;
    tri_decode(r, ti, tj);
    int wave = threadIdx.x >> 6, lane = threadIdx.x & 63;
    int l16 = lane & 15, quad = lane >> 4;
    int rbase = b * 2048 + ti * 128 + wave * 32;
    int cbase = b * 2048 + tj * 128;
    f32x4 acc[2][8] = {};
#pragma unroll
    for (int kc = 0; kc < 64; kc += 32) {
        int ko = kc + quad * 8;
        bf16x8 af[2], bf[8];
#pragma unroll
        for (int f = 0; f < 2; f++)
            af[f] = *reinterpret_cast<const bf16x8*>(Qb + (long)(rbase + f * 16 + l16) * 64 + ko);
#pragma unroll
        for (int f = 0; f < 8; f++)
            bf[f] = *reinterpret_cast<const bf16x8*>(Kb + (long)(cbase + f * 16 + l16) * 64 + ko);
#pragma unroll
        for (int i = 0; i < 2; i++)
#pragma unroll
            for (int j = 0; j < 8; j++)
                acc[i][j] = __builtin_amdgcn_mfma_f32_16x16x32_bf16(af[i], bf[j], acc[i][j], 0, 0, 0);
    }
    int colt = tj * 128;
#pragma unroll
    for (int i = 0; i < 2; i++)
#pragma unroll
        for (int j = 0; j < 8; j++)
#pragma unroll
            for (int rr = 0; rr < 4; rr++) {
                long rowg = rbase + i * 16 + quad * 4 + rr;
                int col = colt + j * 16 + l16;
                compat[rowg * 2048 + col] = (ushort_t)f2bf(acc[i][j][rr]);
            }
}

// ---------------- K3: strip kernel, iteration T (T = # charge components in sg).
// 512 blocks = 4 batches x 128 complementary strip-pairs:
//   strip A rows [8p, 8p+8), strip B rows [2040-8p, 2048-8p) -> constant work/block.
// Pass 1: local L per row (exp over causal cols, full row in-block -> no global L).
// Pass 2: column partials received_part -> Rpart[bid][2048], plain stores.
template <int T>
__global__ __launch_bounds__(256, 4) void k_strip(const ushort_t* __restrict__ compat,
        const float4* __restrict__ charges4, const float* __restrict__ stepp,
        float* __restrict__ Rpart) {
    __shared__ float chA[4][8], chB[4][8], LiA[8], LiB[8], red[4][8];
    int bid = blockIdx.x, tid = threadIdx.x;
    int b = bid >> 7, pi = bid & 127;
    int r0A = pi * 8, r0B = 2040 - pi * 8;
    int jmaxA = (r0A + 8 + 511) >> 9, jmaxB = (r0B + 8 + 511) >> 9;
    int jU = jmaxA > jmaxB ? jmaxA : jmaxB;
    float step = stepp[0];
    if (T > 0 && tid < 16) {
        int rr = tid & 7;
        float4 c4 = charges4[b * 2048 + ((tid < 8) ? r0A : r0B) + rr];
        float (*ch)[8] = (tid < 8) ? chA : chB;
        ch[0][rr] = step * c4.x;
        if (T > 1) ch[1][rr] = step * c4.y;
        if (T > 2) ch[2][rr] = step * c4.z;
        if (T > 3) ch[3][rr] = step * c4.w;
    }
    __syncthreads();
    int colb = tid * 2;
    int w = tid >> 6, lane = tid & 63;
    float4 ca[4], cb4[4];
    if (T > 0) {
        for (int jj = 0; jj < jU; jj++) {
            int col = jj * 512 + colb;
            ca[jj] = charges4[b * 2048 + col];
            cb4[jj] = charges4[b * 2048 + col + 1];
        }
    }
    auto pass1 = [&](int r0, int jmax, const float (*ch)[8], float* Li) {
        float S[8] = {};
        for (int jj = 0; jj < jmax; jj++) {
            int col = jj * 512 + colb;
            const ushort_t* cp = compat + (long)(b * 2048 + r0) * 2048 + col;
#pragma unroll
            for (int rr = 0; rr < 8; rr++) {
                unsigned v = *reinterpret_cast<const unsigned*>(cp + (long)rr * 2048);
                float c0 = bf2f((ushort_t)(v & 0xffffu)), c1 = bf2f((ushort_t)(v >> 16));
                float sg0 = 1.f, sg1 = 1.f;
                if (T > 0) { sg0 += ch[0][rr] * ca[jj].x; sg1 += ch[0][rr] * cb4[jj].x; }
                if (T > 1) { sg0 += ch[1][rr] * ca[jj].y; sg1 += ch[1][rr] * cb4[jj].y; }
                if (T > 2) { sg0 += ch[2][rr] * ca[jj].z; sg1 += ch[2][rr] * cb4[jj].z; }
                if (T > 3) { sg0 += ch[3][rr] * ca[jj].w; sg1 += ch[3][rr] * cb4[jj].w; }
                float p0 = (col <= r0 + rr) ? __expf(c0 * sg0) : 0.f;
                float p1 = (col + 1 <= r0 + rr) ? __expf(c1 * sg1) : 0.f;
                S[rr] += p0 + p1;
            }
        }
#pragma unroll
        for (int rr = 0; rr < 8; rr++) {
            float s = S[rr];
            s += __shfl_xor(s, 1); s += __shfl_xor(s, 2); s += __shfl_xor(s, 4);
            s += __shfl_xor(s, 8); s += __shfl_xor(s, 16); s += __shfl_xor(s, 32);
            if (lane == 0) red[w][rr] = s;
        }
        __syncthreads();
        if (tid < 8)
            Li[tid] = 1.f / fmaxf(red[0][tid] + red[1][tid] + red[2][tid] + red[3][tid], 1e-30f);
        __syncthreads();
    };
    pass1(r0A, jmaxA, chA, LiA);
    pass1(r0B, jmaxB, chB, LiB);

    for (int jj = 0; jj < 4; jj++) {
        int col = jj * 512 + colb;
        float a0 = 0.f, a1 = 0.f;
        if (jj < jmaxA) {
            const ushort_t* cp = compat + (long)(b * 2048 + r0A) * 2048 + col;
#pragma unroll
            for (int rr = 0; rr < 8; rr++) {
                unsigned v = *reinterpret_cast<const unsigned*>(cp + (long)rr * 2048);
                float c0 = bf2f((ushort_t)(v & 0xffffu)), c1 = bf2f((ushort_t)(v >> 16));
                float sg0 = 1.f, sg1 = 1.f;
                if (T > 0) { sg0 += chA[0][rr] * ca[jj].x; sg1 += chA[0][rr] * cb4[jj].x; }
                if (T > 1) { sg0 += chA[1][rr] * ca[jj].y; sg1 += chA[1][rr] * cb4[jj].y; }
                if (T > 2) { sg0 += chA[2][rr] * ca[jj].z; sg1 += chA[2][rr] * cb4[jj].z; }
                if (T > 3) { sg0 += chA[3][rr] * ca[jj].w; sg1 += chA[3][rr] * cb4[jj].w; }
                float li = LiA[rr];
                a0 += (col <= r0A + rr) ? __expf(c0 * sg0) * li : 0.f;
                a1 += (col + 1 <= r0A + rr) ? __expf(c1 * sg1) * li : 0.f;
            }
        }
        if (jj < jmaxB) {
            const ushort_t* cp = compat + (long)(b * 2048 + r0B) * 2048 + col;
#pragma unroll
            for (int rr = 0; rr < 8; rr++) {
                unsigned v = *reinterpret_cast<const unsigned*>(cp + (long)rr * 2048);
                float c0 = bf2f((ushort_t)(v & 0xffffu)), c1 = bf2f((ushort_t)(v >> 16));
                float sg0 = 1.f, sg1 = 1.f;
                if (T > 0) { sg0 += chB[0][rr] * ca[jj].x; sg1 += chB[0][rr] * cb4[jj].x; }
                if (T > 1) { sg0 += chB[1][rr] * ca[jj].y; sg1 += chB[1][rr] * cb4[jj].y; }
                if (T > 2) { sg0 += chB[2][rr] * ca[jj].z; sg1 += chB[2][rr] * cb4[jj].z; }
                if (T > 3) { sg0 += chB[3][rr] * ca[jj].w; sg1 += chB[3][rr] * cb4[jj].w; }
                float li = LiB[rr];
                a0 += (col <= r0B + rr) ? __expf(c0 * sg0) * li : 0.f;
                a1 += (col + 1 <= r0B + rr) ? __expf(c1 * sg1) * li : 0.f;
            }
        }
        *reinterpret_cast<float2*>(&Rpart[(long)bid * 2048 + col]) = make_float2(a0, a1);
    }
}

// ---------------- K4: charge update T (sums 128 strip partials per column)
template <int T>
__global__ void k_charge(const float* __restrict__ Rpart, const float* __restrict__ charge0,
                         float4* __restrict__ charges4, const float* __restrict__ decayp) {
    int m = blockIdx.x * 256 + threadIdx.x;  // 8192
    int b = m >> 11, col = m & 2047;
    const float* rp = Rpart + (long)(b * 128) * 2048 + col;
    float s = 0.f;
    for (int pi = 0; pi < 128; pi++) s += rp[(long)pi * 2048];
    float decay = decayp[0];
    float prev = (T == 1) ? charge0[m] : ((const float*)&charges4[m])[T - 2];
    ((float*)&charges4[m])[T - 1] = prev * (1.f - decay * sigm(s - 1.f));
}

// ---------------- K5: final pass (T=4): local L, normalized p -> LDS -> PV MFMA -> Abf
__global__ __launch_bounds__(256, 4) void k_stripPV(const ushort_t* __restrict__ compat,
        const float4* __restrict__ charges4, const float* __restrict__ stepp,
        const ushort_t* __restrict__ VbT, ushort_t* __restrict__ Abf) {
    __shared__ float chA[4][8], chB[4][8], LiA[8], LiB[8], red[4][8];
    __shared__ ushort_t pbuf[16][536];
    int bid = blockIdx.x, tid = threadIdx.x;
    int b = bid >> 7, pi = bid & 127;
    int r0A = pi * 8, r0B = 2040 - pi * 8;
    int jmaxA = (r0A + 8 + 511) >> 9, jmaxB = (r0B + 8 + 511) >> 9;
    int jU = jmaxA > jmaxB ? jmaxA : jmaxB;
    float step = stepp[0];
    if (tid < 16) {
        int rr = tid & 7;
        float4 c4 = charges4[b * 2048 + ((tid < 8) ? r0A : r0B) + rr];
        float (*ch)[8] = (tid < 8) ? chA : chB;
        ch[0][rr] = step * c4.x; ch[1][rr] = step * c4.y;
        ch[2][rr] = step * c4.z; ch[3][rr] = step * c4.w;
    }
    __syncthreads();
    int colb = tid * 2;
    int w = tid >> 6, lane = tid & 63, l16 = lane & 15, quad = lane >> 4;
    float4 ca[4], cb4[4];
    for (int jj = 0; jj < jU; jj++) {
        int col = jj * 512 + colb;
        ca[jj] = charges4[b * 2048 + col];
        cb4[jj] = charges4[b * 2048 + col + 1];
    }
    auto pass1 = [&](int r0, int jmax, const float (*ch)[8], float* Li) {
        float S[8] = {};
        for (int jj = 0; jj < jmax; jj++) {
            int col = jj * 512 + colb;
            const ushort_t* cp = compat + (long)(b * 2048 + r0) * 2048 + col;
#pragma unroll
            for (int rr = 0; rr < 8; rr++) {
                unsigned v = *reinterpret_cast<const unsigned*>(cp + (long)rr * 2048);
                float c0 = bf2f((ushort_t)(v & 0xffffu)), c1 = bf2f((ushort_t)(v >> 16));
                float sg0 = 1.f + ch[0][rr] * ca[jj].x + ch[1][rr] * ca[jj].y
                                + ch[2][rr] * ca[jj].z + ch[3][rr] * ca[jj].w;
                float sg1 = 1.f + ch[0][rr] * cb4[jj].x + ch[1][rr] * cb4[jj].y
                                + ch[2][rr] * cb4[jj].z + ch[3][rr] * cb4[jj].w;
                float p0 = (col <= r0 + rr) ? __expf(c0 * sg0) : 0.f;
                float p1 = (col + 1 <= r0 + rr) ? __expf(c1 * sg1) : 0.f;
                S[rr] += p0 + p1;
            }
        }
#pragma unroll
        for (int rr = 0; rr < 8; rr++) {
            float s = S[rr];
            s += __shfl_xor(s, 1); s += __shfl_xor(s, 2); s += __shfl_xor(s, 4);
            s += __shfl_xor(s, 8); s += __shfl_xor(s, 16); s += __shfl_xor(s, 32);
            if (lane == 0) red[w][rr] = s;
        }
        __syncthreads();
        if (tid < 8)
            Li[tid] = 1.f / fmaxf(red[0][tid] + red[1][tid] + red[2][tid] + red[3][tid], 1e-30f);
        __syncthreads();
    };
    pass1(r0A, jmaxA, chA, LiA);
    pass1(r0B, jmaxB, chB, LiB);

    f32x4 acc = {};
    for (int jj = 0; jj < jU; jj++) {
        int col = jj * 512 + colb;
        // strip A -> pbuf rows 0-7 (zeros when masked/out of range)
#pragma unroll
        for (int rr = 0; rr < 8; rr++) {
            float p0 = 0.f, p1 = 0.f;
            if (jj < jmaxA) {
                const ushort_t* cp = compat + (long)(b * 2048 + r0A + rr) * 2048 + col;
                unsigned v = *reinterpret_cast<const unsigned*>(cp);
                float c0 = bf2f((ushort_t)(v & 0xffffu)), c1 = bf2f((ushort_t)(v >> 16));
                float sg0 = 1.f + chA[0][rr] * ca[jj].x + chA[1][rr] * ca[jj].y
                                + chA[2][rr] * ca[jj].z + chA[3][rr] * ca[jj].w;
                float sg1 = 1.f + chA[0][rr] * cb4[jj].x + chA[1][rr] * cb4[jj].y
                                + chA[2][rr] * cb4[jj].z + chA[3][rr] * cb4[jj].w;
                float li = LiA[rr];
                p0 = (col <= r0A + rr) ? __expf(c0 * sg0) * li : 0.f;
                p1 = (col + 1 <= r0A + rr) ? __expf(c1 * sg1) * li : 0.f;
            }
            *reinterpret_cast<unsigned*>(&pbuf[rr][colb]) = pk2(p0, p1);
        }
        // strip B -> pbuf rows 8-15
#pragma unroll
        for (int rr = 0; rr < 8; rr++) {
            float p0 = 0.f, p1 = 0.f;
            if (jj < jmaxB) {
                const ushort_t* cp = compat + (long)(b * 2048 + r0B + rr) * 2048 + col;
                unsigned v = *reinterpret_cast<const unsigned*>(cp);
                float c0 = bf2f((ushort_t)(v & 0xffffu)), c1 = bf2f((ushort_t)(v >> 16));
                float sg0 = 1.f + chB[0][rr] * ca[jj].x + chB[1][rr] * ca[jj].y
                                + chB[2][rr] * ca[jj].z + chB[3][rr] * ca[jj].w;
                float sg1 = 1.f + chB[0][rr] * cb4[jj].x + chB[1][rr] * cb4[jj].y
                                + chB[2][rr] * cb4[jj].z + chB[3][rr] * cb4[jj].w;
                float li = LiB[rr];
                p0 = (col <= r0B + rr) ? __expf(c0 * sg0) * li : 0.f;
                p1 = (col + 1 <= r0B + rr) ? __expf(c1 * sg1) * li : 0.f;
            }
            *reinterpret_cast<unsigned*>(&pbuf[8 + rr][colb]) = pk2(p0, p1);
        }
        __syncthreads();
        // PV MFMA: wave w owns d-tile w (16 dims); A = pbuf 16 rows, K = 512 chunk
#pragma unroll
        for (int k0 = 0; k0 < 512; k0 += 32) {
            bf16x8 af = *reinterpret_cast<const bf16x8*>(&pbuf[l16][k0 + quad * 8]);
            bf16x8 vf = *reinterpret_cast<const bf16x8*>(
                VbT + (long)(w * 16 + l16) * 8192 + b * 2048 + jj * 512 + k0 + quad * 8);
            acc = __builtin_amdgcn_mfma_f32_16x16x32_bf16(af, vf, acc, 0, 0, 0);
        }
        __syncthreads();
    }
#pragma unroll
    for (int rr = 0; rr < 4; rr++) {
        int row16 = quad * 4 + rr;
        int grow = (row16 < 8) ? (b * 2048 + r0A + row16) : (b * 2048 + r0B + row16 - 8);
        Abf[(long)grow * 64 + w * 16 + l16] = (ushort_t)f2bf(acc[rr]);
    }
}

// ---------------- K6: out = (Abf @ Wo^T) * 0.1, fp32 store
__global__ __launch_bounds__(256) void k_oproj(const ushort_t* __restrict__ Abf,
                                               const float* __restrict__ Wo,
                                               float* __restrict__ out) {
    int mt = blockIdx.x & 63, nt = blockIdx.x >> 6;
    int wave = threadIdx.x >> 6, lane = threadIdx.x & 63;
    int wm = wave >> 1, wn = wave & 1;
    int l16 = lane & 15, quad = lane >> 4;
    int row0 = mt * 128 + wm * 64;
    int col0 = nt * 128 + wn * 64;
    f32x4 acc[4][4] = {};
#pragma unroll
    for (int kc = 0; kc < 64; kc += 32) {
        int ko = kc + quad * 8;
        bf16x8 af[4], bfm[4];
#pragma unroll
        for (int f = 0; f < 4; f++)
            af[f] = *reinterpret_cast<const bf16x8*>(Abf + (long)(row0 + f * 16 + l16) * 64 + ko);
#pragma unroll
        for (int f = 0; f < 4; f++) bfm[f] = ld8f(Wo + (long)(col0 + f * 16 + l16) * 64 + ko);
#pragma unroll
        for (int i = 0; i < 4; i++)
#pragma unroll
            for (int j = 0; j < 4; j++)
                acc[i][j] = __builtin_amdgcn_mfma_f32_16x16x32_bf16(af[i], bfm[j], acc[i][j], 0, 0, 0);
    }
#pragma unroll
    for (int i = 0; i < 4; i++)
#pragma unroll
        for (int j = 0; j < 4; j++)
#pragma unroll
            for (int rr = 0; rr < 4; rr++) {
                long rowg = row0 + i * 16 + quad * 4 + rr;
                int colg = col0 + j * 16 + l16;
                out[rowg * 1024 + colg] = acc[i][j][rr] * 0.1f;
            }
}

extern "C" void kernel_launch(void* const* d_in, const int* in_sizes, int n_in,
                              void* d_out, int out_size, void* d_ws, size_t ws_size,
                              hipStream_t stream) {
    const float* hidden = (const float*)d_in[0];
    const float* W1 = (const float*)d_in[1];
    const float* b1 = (const float*)d_in[2];
    const float* W2 = (const float*)d_in[3];
    const float* b2 = (const float*)d_in[4];
    const float* Wq = (const float*)d_in[5];
    const float* Wk = (const float*)d_in[6];
    const float* Wc = (const float*)d_in[7];
    const float* bc = (const float*)d_in[8];
    const float* Wv = (const float*)d_in[9];
    const float* Wo = (const float*)d_in[10];
    const float* stepp = (const float*)d_in[11];
    const float* decayp = (const float*)d_in[12];

    char* ws = (char*)d_ws;
    size_t off = 0;
    auto alloc = [&](size_t bytes) {
        void* p = ws + off;
        off += (bytes + 255) & ~(size_t)255;
        return p;
    };
    ushort_t* compat = (ushort_t*)alloc(8192UL * 2048 * 2);   // 32 MiB bf16
    ushort_t* Wcat = (ushort_t*)alloc(128UL * 1024 * 2);      // W1;Wv bf16
    ushort_t* Qb = (ushort_t*)alloc(8192UL * 64 * 2);
    ushort_t* Kb = (ushort_t*)alloc(8192UL * 64 * 2);
    ushort_t* VbT = (ushort_t*)alloc(64UL * 8192 * 2);
    float* charge0 = (float*)alloc(8192UL * 4);
    float4* charges4 = (float4*)alloc(8192UL * 16);
    float* Rpart = (float*)alloc(512UL * 2048 * 4);           // 4 MiB col partials
    ushort_t* Abf = (ushort_t*)alloc(8192UL * 64 * 2);        // 1 MiB normalized O
    (void)ws_size; (void)in_sizes; (void)n_in; (void)out_size;

    k_cvtW<<<64, 256, 0, stream>>>(W1, Wv, Wcat);
    k_fvfeat<<<512, 256, 0, stream>>>(hidden, Wcat, b1, W2, b2, Wq, Wk, Wc, bc,
                                      Qb, Kb, VbT, charge0);
    k_compat<<<544, 256, 0, stream>>>(Qb, Kb, compat);

    k_strip<0><<<512, 256, 0, stream>>>(compat, charges4, stepp, Rpart);
    k_charge<1><<<32, 256, 0, stream>>>(Rpart, charge0, charges4, decayp);
    k_strip<1><<<512, 256, 0, stream>>>(compat, charges4, stepp, Rpart);
    k_charge<2><<<32, 256, 0, stream>>>(Rpart, charge0, charges4, decayp);
    k_strip<2><<<512, 256, 0, stream>>>(compat, charges4, stepp, Rpart);
    k_charge<3><<<32, 256, 0, stream>>>(Rpart, charge0, charges4, decayp);
    k_strip<3><<<512, 256, 0, stream>>>(compat, charges4, stepp, Rpart);
    k_charge<4><<<32, 256, 0, stream>>>(Rpart, charge0, charges4, decayp);

    k_stripPV<<<512, 256, 0, stream>>>(compat, charges4, stepp, VbT, Abf);
    k_oproj<<<512, 256, 0, stream>>>(Abf, Wo, (float*)d_out);
}

// Round 8
// 280.502 us; speedup vs baseline: 3.0636x; 1.3543x over previous
//
#include <hip/hip_runtime.h>
#include <hip/hip_bf16.h>

typedef unsigned short ushort_t;
typedef short bf16x8 __attribute__((ext_vector_type(8)));
typedef ushort_t u16x8 __attribute__((ext_vector_type(8)));
typedef ushort_t u16x4 __attribute__((ext_vector_type(4)));
typedef float f32x4 __attribute__((ext_vector_type(4)));

#define DEV static __device__ __forceinline__

DEV float bf2f(ushort_t u) { unsigned v = ((unsigned)u) << 16; float f; __builtin_memcpy(&f, &v, 4); return f; }
DEV short f2bf(float x) { __hip_bfloat16 h = __float2bfloat16(x); short s; __builtin_memcpy(&s, &h, 2); return s; }
DEV float sigm(float x) { return 1.0f / (1.0f + __expf(-x)); }

DEV bf16x8 cvt8(float4 a0, float4 a1) {
    bf16x8 t;
    t[0] = f2bf(a0.x); t[1] = f2bf(a0.y); t[2] = f2bf(a0.z); t[3] = f2bf(a0.w);
    t[4] = f2bf(a1.x); t[5] = f2bf(a1.y); t[6] = f2bf(a1.z); t[7] = f2bf(a1.w);
    return t;
}
DEV bf16x8 ld8f(const float* __restrict__ p) {
    return cvt8(*reinterpret_cast<const float4*>(p), *reinterpret_cast<const float4*>(p + 4));
}

// ---------------- K0: fp32 -> bf16 for W1, Wv only
__global__ void k_cvtW(const float* __restrict__ W1, const float* __restrict__ Wv,
                       ushort_t* __restrict__ Wcat) {
    int i = blockIdx.x * 256 + threadIdx.x;  // 16384 threads, 8 elems each
    const float* src = (i < 8192) ? (W1 + (long)i * 8) : (Wv + (long)(i - 8192) * 8);
    const float4* p = reinterpret_cast<const float4*>(src);
    *reinterpret_cast<bf16x8*>(Wcat + (long)i * 8) = cvt8(p[0], p[1]);
}

// ---------------- K1: fused fv+feat. 512 blocks x 16 rows.
__global__ __launch_bounds__(256) void k_fvfeat(const float* __restrict__ hidden,
        const ushort_t* __restrict__ Wcat, const float* __restrict__ b1,
        const float* __restrict__ W2, const float* __restrict__ b2,
        const float* __restrict__ Wq, const float* __restrict__ Wk,
        const float* __restrict__ Wc, const float* __restrict__ bc,
        ushort_t* __restrict__ Qb, ushort_t* __restrict__ Kb,
        ushort_t* __restrict__ VbT, float* __restrict__ charge0) {
    __shared__ float w2L[28 * 65], wqL[64 * 29], wkL[64 * 29], wcL[28], b2L[28];
    __shared__ float fLDS[16][65], featL[4][28];
    int tid = threadIdx.x;
    for (int i = tid; i < 28 * 64; i += 256) w2L[(i >> 6) * 65 + (i & 63)] = W2[i];
    for (int i = tid; i < 64 * 28; i += 256) {
        int r = i / 28, c = i - r * 28;
        wqL[r * 29 + c] = Wq[i];
        wkL[r * 29 + c] = Wk[i];
    }
    if (tid < 28) { wcL[tid] = Wc[tid]; b2L[tid] = b2[tid]; }

    int m0 = blockIdx.x * 16;
    int wave = tid >> 6, lane = tid & 63, l16 = lane & 15, quad = lane >> 4;
    int cb = (wave & 1) * 32;
    int brow_off = (wave < 2) ? 0 : 64;   // Wcat rows 0-63 = W1, 64-127 = Wv
    f32x4 acc[2] = {};
    const float* arow = hidden + (long)(m0 + l16) * 1024;
    const ushort_t* brow0 = Wcat + (long)(brow_off + cb + l16) * 1024;
    const ushort_t* brow1 = Wcat + (long)(brow_off + cb + 16 + l16) * 1024;
    for (int kc = 0; kc < 1024; kc += 128) {
#pragma unroll
        for (int u = 0; u < 4; u++) {
            int ko = kc + u * 32 + quad * 8;
            bf16x8 a = ld8f(arow + ko);
            bf16x8 b0 = *reinterpret_cast<const bf16x8*>(brow0 + ko);
            bf16x8 b1f = *reinterpret_cast<const bf16x8*>(brow1 + ko);
            acc[0] = __builtin_amdgcn_mfma_f32_16x16x32_bf16(a, b0, acc[0], 0, 0, 0);
            acc[1] = __builtin_amdgcn_mfma_f32_16x16x32_bf16(a, b1f, acc[1], 0, 0, 0);
        }
    }
    if (wave < 2) {
        float b1a = b1[cb + l16], b1b = b1[cb + 16 + l16];
#pragma unroll
        for (int c = 0; c < 2; c++) {
            float bv = c ? b1b : b1a;
#pragma unroll
            for (int rr = 0; rr < 4; rr++) {
                float x = acc[c][rr] + bv;
                fLDS[quad * 4 + rr][cb + c * 16 + l16] =
                    0.5f * x * (1.0f + erff(x * 0.70710678118654752f));
            }
        }
    } else {
#pragma unroll
        for (int c = 0; c < 2; c++)
#pragma unroll
            for (int rr = 0; rr < 4; rr++)
                VbT[(long)(cb + c * 16 + l16) * 8192 + (m0 + quad * 4 + rr)] =
                    (ushort_t)f2bf(acc[c][rr]);
    }
    __syncthreads();
    float bcv = bc[0];
    for (int it = 0; it < 4; it++) {
        int rowl = it * 4 + wave;
        int row = m0 + rowl;
        if (lane < 28) {
            float s = b2L[lane];
#pragma unroll
            for (int j = 0; j < 64; j++) s += fLDS[rowl][j] * w2L[lane * 65 + j];
            featL[wave][lane] = sigm(s);
        }
        __syncthreads();
        float q = 0.f, k = 0.f;
#pragma unroll
        for (int i = 0; i < 28; i++) {
            float fv = featL[wave][i];
            q += fv * wqL[lane * 29 + i];
            k += fv * wkL[lane * 29 + i];
        }
        Qb[row * 64 + lane] = (ushort_t)f2bf(q * 0.125f);  // fold 1/sqrt(64)
        Kb[row * 64 + lane] = (ushort_t)f2bf(k);
        if (lane == 0) {
            float c = bcv;
#pragma unroll
            for (int i = 0; i < 28; i++) c += featL[wave][i] * wcL[i];
            charge0[row] = sigm(c);
        }
        __syncthreads();
    }
}

DEV void tri_decode(int r, int& ti, int& tj) {
    int t = (int)((sqrtf(8.f * (float)r + 1.f) - 1.f) * 0.5f);
    while ((t + 1) * (t + 2) / 2 <= r) t++;
    while (t * (t + 1) / 2 > r) t--;
    ti = t;
    tj = r - t * (t + 1) / 2;
}

// ---------------- K2: compat = (Q/8)·K, causal 128x128 tiles, bf16
__global__ __launch_bounds__(256) void k_compat(const ushort_t* __restrict__ Qb,
                                                const ushort_t* __restrict__ Kb,
                                                ushort_t* __restrict__ compat) {
    int bid = blockIdx.x;
    int b = bid / 136, r = bid % 136, ti, tj;
    tri_decode(r, ti, tj);
    int wave = threadIdx.x >> 6, lane = threadIdx.x & 63;
    int l16 = lane & 15, quad = lane >> 4;
    int rbase = b * 2048 + ti * 128 + wave * 32;
    int cbase = b * 2048 + tj * 128;
    f32x4 acc[2][8] = {};
#pragma unroll
    for (int kc = 0; kc < 64; kc += 32) {
        int ko = kc + quad * 8;
        bf16x8 af[2], bf[8];
#pragma unroll
        for (int f = 0; f < 2; f++)
            af[f] = *reinterpret_cast<const bf16x8*>(Qb + (long)(rbase + f * 16 + l16) * 64 + ko);
#pragma unroll
        for (int f = 0; f < 8; f++)
            bf[f] = *reinterpret_cast<const bf16x8*>(Kb + (long)(cbase + f * 16 + l16) * 64 + ko);
#pragma unroll
        for (int i = 0; i < 2; i++)
#pragma unroll
            for (int j = 0; j < 8; j++)
                acc[i][j] = __builtin_amdgcn_mfma_f32_16x16x32_bf16(af[i], bf[j], acc[i][j], 0, 0, 0);
    }
    int colt = tj * 128;
#pragma unroll
    for (int i = 0; i < 2; i++)
#pragma unroll
        for (int j = 0; j < 8; j++)
#pragma unroll
            for (int rr = 0; rr < 4; rr++) {
                long rowg = rbase + i * 16 + quad * 4 + rr;
                int col = colt + j * 16 + l16;
                compat[rowg * 2048 + col] = (ushort_t)f2bf(acc[i][j][rr]);
            }
}

// ---------------- K3: single-pass strip kernel, iteration T.
// 1024 blocks = 4 batches x 256 pairs {A rows [4p,4p+4), B rows [2044-4p,2048-4p)}.
// chunk0 cols[0,1024) handles A(masked)+B0(unmasked); chunk1 cols[1024,2048)
// handles B1(masked). p kept in regs (static idx), normalized by in-block L
// after one reduce -> column partials, compat read ONCE.
template <int T>
__global__ __launch_bounds__(256, 2) void k_strip(const ushort_t* __restrict__ compat,
        const float4* __restrict__ charges4, const float* __restrict__ stepp,
        float* __restrict__ Rpart) {
    __shared__ float chR[4][8];   // [comp][row: 0-3 A, 4-7 B]
    __shared__ float red[4][8], Li[8];
    int bid = blockIdx.x, tid = threadIdx.x;
    int b = bid >> 8, pi = bid & 255;
    int r0A = pi * 4, r0B = 2044 - pi * 4;
    float step = stepp[0];
    if (T > 0 && tid < 8) {
        int row = (tid < 4) ? (r0A + tid) : (r0B + tid - 4);
        float4 c4 = charges4[b * 2048 + row];
        chR[0][tid] = step * c4.x;
        if (T > 1) chR[1][tid] = step * c4.y;
        if (T > 2) chR[2][tid] = step * c4.z;
        if (T > 3) chR[3][tid] = step * c4.w;
    }
    __syncthreads();
    int w = tid >> 6, lane = tid & 63;
    int c0 = tid * 4;
    const ushort_t* base = compat + (long)(b * 2048) * 2048;

    float pA[4][4], pB0[4][4], pB1[4][4];
    float SA[4] = {}, SB[4] = {};

    // ---- chunk 0: cols [c0, c0+4) in [0,1024)
    {
        float cx[4] = {}, cy[4] = {}, cz[4] = {}, cw[4] = {};
        if (T > 0) {
#pragma unroll
            for (int k = 0; k < 4; k++) {
                float4 c = charges4[b * 2048 + c0 + k];
                cx[k] = c.x;
                if (T > 1) cy[k] = c.y;
                if (T > 2) cz[k] = c.z;
                if (T > 3) cw[k] = c.w;
            }
        }
#pragma unroll
        for (int rr = 0; rr < 4; rr++) {
            u16x4 v = *reinterpret_cast<const u16x4*>(base + (long)(r0A + rr) * 2048 + c0);
#pragma unroll
            for (int k = 0; k < 4; k++) {
                float sg = 1.f;
                if (T > 0) sg += chR[0][rr] * cx[k];
                if (T > 1) sg += chR[1][rr] * cy[k];
                if (T > 2) sg += chR[2][rr] * cz[k];
                if (T > 3) sg += chR[3][rr] * cw[k];
                float p = (c0 + k <= r0A + rr) ? __expf(bf2f(v[k]) * sg) : 0.f;
                pA[rr][k] = p;
                SA[rr] += p;
            }
        }
#pragma unroll
        for (int rr = 0; rr < 4; rr++) {
            u16x4 v = *reinterpret_cast<const u16x4*>(base + (long)(r0B + rr) * 2048 + c0);
#pragma unroll
            for (int k = 0; k < 4; k++) {
                float sg = 1.f;
                if (T > 0) sg += chR[0][4 + rr] * cx[k];
                if (T > 1) sg += chR[1][4 + rr] * cy[k];
                if (T > 2) sg += chR[2][4 + rr] * cz[k];
                if (T > 3) sg += chR[3][4 + rr] * cw[k];
                float p = __expf(bf2f(v[k]) * sg);   // col<1024 <= r0B always
                pB0[rr][k] = p;
                SB[rr] += p;
            }
        }
    }
    // ---- chunk 1: cols 1024+[c0, c0+4), B rows only (masked)
    {
        float cx[4] = {}, cy[4] = {}, cz[4] = {}, cw[4] = {};
        if (T > 0) {
#pragma unroll
            for (int k = 0; k < 4; k++) {
                float4 c = charges4[b * 2048 + 1024 + c0 + k];
                cx[k] = c.x;
                if (T > 1) cy[k] = c.y;
                if (T > 2) cz[k] = c.z;
                if (T > 3) cw[k] = c.w;
            }
        }
#pragma unroll
        for (int rr = 0; rr < 4; rr++) {
            u16x4 v = *reinterpret_cast<const u16x4*>(base + (long)(r0B + rr) * 2048 + 1024 + c0);
#pragma unroll
            for (int k = 0; k < 4; k++) {
                float sg = 1.f;
                if (T > 0) sg += chR[0][4 + rr] * cx[k];
                if (T > 1) sg += chR[1][4 + rr] * cy[k];
                if (T > 2) sg += chR[2][4 + rr] * cz[k];
                if (T > 3) sg += chR[3][4 + rr] * cw[k];
                float p = (1024 + c0 + k <= r0B + rr) ? __expf(bf2f(v[k]) * sg) : 0.f;
                pB1[rr][k] = p;
                SB[rr] += p;
            }
        }
    }
    // ---- reduce row sums -> Li[8]
#pragma unroll
    for (int rr = 0; rr < 4; rr++) {
        float s = SA[rr];
        s += __shfl_xor(s, 1); s += __shfl_xor(s, 2); s += __shfl_xor(s, 4);
        s += __shfl_xor(s, 8); s += __shfl_xor(s, 16); s += __shfl_xor(s, 32);
        if (lane == 0) red[w][rr] = s;
        float t = SB[rr];
        t += __shfl_xor(t, 1); t += __shfl_xor(t, 2); t += __shfl_xor(t, 4);
        t += __shfl_xor(t, 8); t += __shfl_xor(t, 16); t += __shfl_xor(t, 32);
        if (lane == 0) red[w][4 + rr] = t;
    }
    __syncthreads();
    if (tid < 8) Li[tid] = 1.f / fmaxf(red[0][tid] + red[1][tid] + red[2][tid] + red[3][tid], 1e-30f);
    __syncthreads();
    float liA0 = Li[0], liA1 = Li[1], liA2 = Li[2], liA3 = Li[3];
    float liB0 = Li[4], liB1 = Li[5], liB2 = Li[6], liB3 = Li[7];
    float4 o0, o1;
    float* po0 = (float*)&o0;
    float* po1 = (float*)&o1;
#pragma unroll
    for (int k = 0; k < 4; k++) {
        po0[k] = pA[0][k] * liA0 + pA[1][k] * liA1 + pA[2][k] * liA2 + pA[3][k] * liA3
               + pB0[0][k] * liB0 + pB0[1][k] * liB1 + pB0[2][k] * liB2 + pB0[3][k] * liB3;
        po1[k] = pB1[0][k] * liB0 + pB1[1][k] * liB1 + pB1[2][k] * liB2 + pB1[3][k] * liB3;
    }
    *reinterpret_cast<float4*>(&Rpart[(long)bid * 2048 + c0]) = o0;
    *reinterpret_cast<float4*>(&Rpart[(long)bid * 2048 + 1024 + c0]) = o1;
}

// ---------------- K4: charge update T. 256 blocks; block = 32 cols x 8 partial-groups.
template <int T>
__global__ __launch_bounds__(256) void k_charge(const float* __restrict__ Rpart,
        const float* __restrict__ charge0, float4* __restrict__ charges4,
        const float* __restrict__ decayp) {
    __shared__ float s8[8][33];
    int g = threadIdx.x >> 5, cl = threadIdx.x & 31;
    int m = blockIdx.x * 32 + cl;           // global col id in [0,8192)
    int b = m >> 11, col = m & 2047;
    const float* rp = Rpart + ((long)(b * 256 + g * 32) * 2048) + col;
    float s = 0.f;
#pragma unroll
    for (int i = 0; i < 32; i++) s += rp[(long)i * 2048];
    s8[g][cl] = s;
    __syncthreads();
    if (threadIdx.x < 32) {
        float t = 0.f;
#pragma unroll
        for (int gg = 0; gg < 8; gg++) t += s8[gg][threadIdx.x];
        int mm = blockIdx.x * 32 + threadIdx.x;
        float decay = decayp[0];
        float prev = (T == 1) ? charge0[mm] : ((const float*)&charges4[mm])[T - 2];
        ((float*)&charges4[mm])[T - 1] = prev * (1.f - decay * sigm(t - 1.f));
    }
}

// ---------------- K5: final pass, single-pass PV with deferred normalization.
// 512 blocks = 4 batches x 128 pairs {A rows [8p,8p+8), B rows [2040-8p,2048-8p)}.
// chunk0 cols[0,1024): 16 valid rows; chunk1 cols[1024,2048): 8 B rows + 8 zeros.
// p -> pbuf bf16 unnormalized; MFMA accumulates; acc scaled by 1/L at writeout.
// pbuf row stride 1032 shorts = 2064 B = 129*16: 16B-aligned (ds_read_b128 legal;
// 1026 was the round-7 fault) and odd multiple of 16B -> worst 2-way bank alias.
__global__ __launch_bounds__(256, 2) void k_stripPV(const ushort_t* __restrict__ compat,
        const float4* __restrict__ charges4, const float* __restrict__ stepp,
        const ushort_t* __restrict__ VbT, ushort_t* __restrict__ Abf) {
    __shared__ float chR[4][16], red[4][16], Li[16];
    __shared__ __align__(16) ushort_t pbuf[16][1032];
    int bid = blockIdx.x, tid = threadIdx.x;
    int b = bid >> 7, pi = bid & 127;
    int r0A = pi * 8, r0B = 2040 - pi * 8;
    float step = stepp[0];
    if (tid < 16) {
        int row = (tid < 8) ? (r0A + tid) : (r0B + tid - 8);
        float4 c4 = charges4[b * 2048 + row];
        chR[0][tid] = step * c4.x; chR[1][tid] = step * c4.y;
        chR[2][tid] = step * c4.z; chR[3][tid] = step * c4.w;
    }
    __syncthreads();
    int w = tid >> 6, lane = tid & 63, l16 = lane & 15, quad = lane >> 4;
    int c0 = tid * 4;
    const ushort_t* base = compat + (long)(b * 2048) * 2048;
    float S[16];
#pragma unroll
    for (int i = 0; i < 16; i++) S[i] = 0.f;
    f32x4 acc = {};

    // ---- chunk 0: cols [0,1024)
    {
        float cx[4], cy[4], cz[4], cw[4];
#pragma unroll
        for (int k = 0; k < 4; k++) {
            float4 c = charges4[b * 2048 + c0 + k];
            cx[k] = c.x; cy[k] = c.y; cz[k] = c.z; cw[k] = c.w;
        }
#pragma unroll
        for (int i = 0; i < 16; i++) {
            int grow = (i < 8) ? (r0A + i) : (r0B + i - 8);
            u16x4 v = *reinterpret_cast<const u16x4*>(base + (long)grow * 2048 + c0);
            u16x4 pv;
#pragma unroll
            for (int k = 0; k < 4; k++) {
                float sg = 1.f + chR[0][i] * cx[k] + chR[1][i] * cy[k]
                               + chR[2][i] * cz[k] + chR[3][i] * cw[k];
                float p = __expf(bf2f(v[k]) * sg);
                if (i < 8 && (c0 + k > r0A + i)) p = 0.f;
                S[i] += p;
                pv[k] = (ushort_t)f2bf(p);
            }
            *reinterpret_cast<u16x4*>(&pbuf[i][c0]) = pv;
        }
    }
    __syncthreads();
#pragma unroll
    for (int k0 = 0; k0 < 1024; k0 += 32) {
        bf16x8 af = *reinterpret_cast<const bf16x8*>(&pbuf[l16][k0 + quad * 8]);
        bf16x8 vf = *reinterpret_cast<const bf16x8*>(
            VbT + (long)(w * 16 + l16) * 8192 + b * 2048 + k0 + quad * 8);
        acc = __builtin_amdgcn_mfma_f32_16x16x32_bf16(af, vf, acc, 0, 0, 0);
    }
    __syncthreads();
    // ---- chunk 1: cols [1024,2048): B rows masked; A rows zeroed
    {
        float cx[4], cy[4], cz[4], cw[4];
#pragma unroll
        for (int k = 0; k < 4; k++) {
            float4 c = charges4[b * 2048 + 1024 + c0 + k];
            cx[k] = c.x; cy[k] = c.y; cz[k] = c.z; cw[k] = c.w;
        }
        u16x4 z = {0, 0, 0, 0};
#pragma unroll
        for (int i = 0; i < 8; i++) *reinterpret_cast<u16x4*>(&pbuf[i][c0]) = z;
#pragma unroll
        for (int i = 8; i < 16; i++) {
            int grow = r0B + i - 8;
            u16x4 v = *reinterpret_cast<const u16x4*>(base + (long)grow * 2048 + 1024 + c0);
            u16x4 pv;
#pragma unroll
            for (int k = 0; k < 4; k++) {
                float sg = 1.f + chR[0][i] * cx[k] + chR[1][i] * cy[k]
                               + chR[2][i] * cz[k] + chR[3][i] * cw[k];
                float p = (1024 + c0 + k <= grow) ? __expf(bf2f(v[k]) * sg) : 0.f;
                S[i] += p;
                pv[k] = (ushort_t)f2bf(p);
            }
            *reinterpret_cast<u16x4*>(&pbuf[i][c0]) = pv;
        }
    }
    __syncthreads();
#pragma unroll
    for (int k0 = 0; k0 < 1024; k0 += 32) {
        bf16x8 af = *reinterpret_cast<const bf16x8*>(&pbuf[l16][k0 + quad * 8]);
        bf16x8 vf = *reinterpret_cast<const bf16x8*>(
            VbT + (long)(w * 16 + l16) * 8192 + b * 2048 + 1024 + k0 + quad * 8);
        acc = __builtin_amdgcn_mfma_f32_16x16x32_bf16(af, vf, acc, 0, 0, 0);
    }
    // ---- reduce S -> Li[16], scale acc, write
#pragma unroll
    for (int i = 0; i < 16; i++) {
        float s = S[i];
        s += __shfl_xor(s, 1); s += __shfl_xor(s, 2); s += __shfl_xor(s, 4);
        s += __shfl_xor(s, 8); s += __shfl_xor(s, 16); s += __shfl_xor(s, 32);
        if (lane == 0) red[w][i] = s;
    }
    __syncthreads();
    if (tid < 16) Li[tid] = 1.f / fmaxf(red[0][tid] + red[1][tid] + red[2][tid] + red[3][tid], 1e-30f);
    __syncthreads();
#pragma unroll
    for (int rr = 0; rr < 4; rr++) {
        int row16 = quad * 4 + rr;
        int grow = (row16 < 8) ? (b * 2048 + r0A + row16) : (b * 2048 + r0B + row16 - 8);
        Abf[(long)grow * 64 + w * 16 + l16] = (ushort_t)f2bf(acc[rr] * Li[row16]);
    }
}

// ---------------- K6: out = (Abf @ Wo^T) * 0.1, fp32 store
__global__ __launch_bounds__(256) void k_oproj(const ushort_t* __restrict__ Abf,
                                               const float* __restrict__ Wo,
                                               float* __restrict__ out) {
    int mt = blockIdx.x & 63, nt = blockIdx.x >> 6;
    int wave = threadIdx.x >> 6, lane = threadIdx.x & 63;
    int wm = wave >> 1, wn = wave & 1;
    int l16 = lane & 15, quad = lane >> 4;
    int row0 = mt * 128 + wm * 64;
    int col0 = nt * 128 + wn * 64;
    f32x4 acc[4][4] = {};
#pragma unroll
    for (int kc = 0; kc < 64; kc += 32) {
        int ko = kc + quad * 8;
        bf16x8 af[4], bfm[4];
#pragma unroll
        for (int f = 0; f < 4; f++)
            af[f] = *reinterpret_cast<const bf16x8*>(Abf + (long)(row0 + f * 16 + l16) * 64 + ko);
#pragma unroll
        for (int f = 0; f < 4; f++) bfm[f] = ld8f(Wo + (long)(col0 + f * 16 + l16) * 64 + ko);
#pragma unroll
        for (int i = 0; i < 4; i++)
#pragma unroll
            for (int j = 0; j < 4; j++)
                acc[i][j] = __builtin_amdgcn_mfma_f32_16x16x32_bf16(af[i], bfm[j], acc[i][j], 0, 0, 0);
    }
#pragma unroll
    for (int i = 0; i < 4; i++)
#pragma unroll
        for (int j = 0; j < 4; j++)
#pragma unroll
            for (int rr = 0; rr < 4; rr++) {
                long rowg = row0 + i * 16 + quad * 4 + rr;
                int colg = col0 + j * 16 + l16;
                out[rowg * 1024 + colg] = acc[i][j][rr] * 0.1f;
            }
}

extern "C" void kernel_launch(void* const* d_in, const int* in_sizes, int n_in,
                              void* d_out, int out_size, void* d_ws, size_t ws_size,
                              hipStream_t stream) {
    const float* hidden = (const float*)d_in[0];
    const float* W1 = (const float*)d_in[1];
    const float* b1 = (const float*)d_in[2];
    const float* W2 = (const float*)d_in[3];
    const float* b2 = (const float*)d_in[4];
    const float* Wq = (const float*)d_in[5];
    const float* Wk = (const float*)d_in[6];
    const float* Wc = (const float*)d_in[7];
    const float* bc = (const float*)d_in[8];
    const float* Wv = (const float*)d_in[9];
    const float* Wo = (const float*)d_in[10];
    const float* stepp = (const float*)d_in[11];
    const float* decayp = (const float*)d_in[12];

    char* ws = (char*)d_ws;
    size_t off = 0;
    auto alloc = [&](size_t bytes) {
        void* p = ws + off;
        off += (bytes + 255) & ~(size_t)255;
        return p;
    };
    ushort_t* compat = (ushort_t*)alloc(8192UL * 2048 * 2);   // 32 MiB bf16
    ushort_t* Wcat = (ushort_t*)alloc(128UL * 1024 * 2);      // W1;Wv bf16
    ushort_t* Qb = (ushort_t*)alloc(8192UL * 64 * 2);
    ushort_t* Kb = (ushort_t*)alloc(8192UL * 64 * 2);
    ushort_t* VbT = (ushort_t*)alloc(64UL * 8192 * 2);
    float* charge0 = (float*)alloc(8192UL * 4);
    float4* charges4 = (float4*)alloc(8192UL * 16);
    float* Rpart = (float*)alloc(1024UL * 2048 * 4);          // 8 MiB col partials
    ushort_t* Abf = (ushort_t*)alloc(8192UL * 64 * 2);        // 1 MiB normalized O
    (void)ws_size; (void)in_sizes; (void)n_in; (void)out_size;

    k_cvtW<<<64, 256, 0, stream>>>(W1, Wv, Wcat);
    k_fvfeat<<<512, 256, 0, stream>>>(hidden, Wcat, b1, W2, b2, Wq, Wk, Wc, bc,
                                      Qb, Kb, VbT, charge0);
    k_compat<<<544, 256, 0, stream>>>(Qb, Kb, compat);

    k_strip<0><<<1024, 256, 0, stream>>>(compat, charges4, stepp, Rpart);
    k_charge<1><<<256, 256, 0, stream>>>(Rpart, charge0, charges4, decayp);
    k_strip<1><<<1024, 256, 0, stream>>>(compat, charges4, stepp, Rpart);
    k_charge<2><<<256, 256, 0, stream>>>(Rpart, charge0, charges4, decayp);
    k_strip<2><<<1024, 256, 0, stream>>>(compat, charges4, stepp, Rpart);
    k_charge<3><<<256, 256, 0, stream>>>(Rpart, charge0, charges4, decayp);
    k_strip<3><<<1024, 256, 0, stream>>>(compat, charges4, stepp, Rpart);
    k_charge<4><<<256, 256, 0, stream>>>(Rpart, charge0, charges4, decayp);

    k_stripPV<<<512, 256, 0, stream>>>(compat, charges4, stepp, VbT, Abf);
    k_oproj<<<512, 256, 0, stream>>>(Abf, Wo, (float*)d_out);
}

// Round 9
// 261.674 us; speedup vs baseline: 3.2840x; 1.0720x over previous
//
#include <hip/hip_runtime.h>
#include <hip/hip_bf16.h>

typedef unsigned short ushort_t;
typedef short bf16x8 __attribute__((ext_vector_type(8)));
typedef ushort_t u16x8 __attribute__((ext_vector_type(8)));
typedef ushort_t u16x4 __attribute__((ext_vector_type(4)));
typedef float f32x4 __attribute__((ext_vector_type(4)));

#define DEV static __device__ __forceinline__

DEV float bf2f(ushort_t u) { unsigned v = ((unsigned)u) << 16; float f; __builtin_memcpy(&f, &v, 4); return f; }
DEV short f2bf(float x) { __hip_bfloat16 h = __float2bfloat16(x); short s; __builtin_memcpy(&s, &h, 2); return s; }
DEV float sigm(float x) { return 1.0f / (1.0f + __expf(-x)); }

DEV bf16x8 cvt8(float4 a0, float4 a1) {
    bf16x8 t;
    t[0] = f2bf(a0.x); t[1] = f2bf(a0.y); t[2] = f2bf(a0.z); t[3] = f2bf(a0.w);
    t[4] = f2bf(a1.x); t[5] = f2bf(a1.y); t[6] = f2bf(a1.z); t[7] = f2bf(a1.w);
    return t;
}
DEV bf16x8 ld8f(const float* __restrict__ p) {
    return cvt8(*reinterpret_cast<const float4*>(p), *reinterpret_cast<const float4*>(p + 4));
}

// ---------------- K0: fp32 -> bf16 for W1, Wv only
__global__ void k_cvtW(const float* __restrict__ W1, const float* __restrict__ Wv,
                       ushort_t* __restrict__ Wcat) {
    int i = blockIdx.x * 256 + threadIdx.x;  // 16384 threads, 8 elems each
    const float* src = (i < 8192) ? (W1 + (long)i * 8) : (Wv + (long)(i - 8192) * 8);
    const float4* p = reinterpret_cast<const float4*>(src);
    *reinterpret_cast<bf16x8*>(Wcat + (long)i * 8) = cvt8(p[0], p[1]);
}

// ---------------- K1: fused fv+feat. 512 blocks x 16 rows.
__global__ __launch_bounds__(256) void k_fvfeat(const float* __restrict__ hidden,
        const ushort_t* __restrict__ Wcat, const float* __restrict__ b1,
        const float* __restrict__ W2, const float* __restrict__ b2,
        const float* __restrict__ Wq, const float* __restrict__ Wk,
        const float* __restrict__ Wc, const float* __restrict__ bc,
        ushort_t* __restrict__ Qb, ushort_t* __restrict__ Kb,
        ushort_t* __restrict__ VbT, float* __restrict__ charge0) {
    __shared__ float w2L[28 * 65], wqL[64 * 29], wkL[64 * 29], wcL[28], b2L[28];
    __shared__ float fLDS[16][65], featL[4][28];
    int tid = threadIdx.x;
    for (int i = tid; i < 28 * 64; i += 256) w2L[(i >> 6) * 65 + (i & 63)] = W2[i];
    for (int i = tid; i < 64 * 28; i += 256) {
        int r = i / 28, c = i - r * 28;
        wqL[r * 29 + c] = Wq[i];
        wkL[r * 29 + c] = Wk[i];
    }
    if (tid < 28) { wcL[tid] = Wc[tid]; b2L[tid] = b2[tid]; }

    int m0 = blockIdx.x * 16;
    int wave = tid >> 6, lane = tid & 63, l16 = lane & 15, quad = lane >> 4;
    int cb = (wave & 1) * 32;
    int brow_off = (wave < 2) ? 0 : 64;   // Wcat rows 0-63 = W1, 64-127 = Wv
    f32x4 acc[2] = {};
    const float* arow = hidden + (long)(m0 + l16) * 1024;
    const ushort_t* brow0 = Wcat + (long)(brow_off + cb + l16) * 1024;
    const ushort_t* brow1 = Wcat + (long)(brow_off + cb + 16 + l16) * 1024;
    for (int kc = 0; kc < 1024; kc += 128) {
#pragma unroll
        for (int u = 0; u < 4; u++) {
            int ko = kc + u * 32 + quad * 8;
            bf16x8 a = ld8f(arow + ko);
            bf16x8 b0 = *reinterpret_cast<const bf16x8*>(brow0 + ko);
            bf16x8 b1f = *reinterpret_cast<const bf16x8*>(brow1 + ko);
            acc[0] = __builtin_amdgcn_mfma_f32_16x16x32_bf16(a, b0, acc[0], 0, 0, 0);
            acc[1] = __builtin_amdgcn_mfma_f32_16x16x32_bf16(a, b1f, acc[1], 0, 0, 0);
        }
    }
    if (wave < 2) {
        float b1a = b1[cb + l16], b1b = b1[cb + 16 + l16];
#pragma unroll
        for (int c = 0; c < 2; c++) {
            float bv = c ? b1b : b1a;
#pragma unroll
            for (int rr = 0; rr < 4; rr++) {
                float x = acc[c][rr] + bv;
                fLDS[quad * 4 + rr][cb + c * 16 + l16] =
                    0.5f * x * (1.0f + erff(x * 0.70710678118654752f));
            }
        }
    } else {
#pragma unroll
        for (int c = 0; c < 2; c++)
#pragma unroll
            for (int rr = 0; rr < 4; rr++)
                VbT[(long)(cb + c * 16 + l16) * 8192 + (m0 + quad * 4 + rr)] =
                    (ushort_t)f2bf(acc[c][rr]);
    }
    __syncthreads();
    float bcv = bc[0];
    for (int it = 0; it < 4; it++) {
        int rowl = it * 4 + wave;
        int row = m0 + rowl;
        if (lane < 28) {
            float s = b2L[lane];
#pragma unroll
            for (int j = 0; j < 64; j++) s += fLDS[rowl][j] * w2L[lane * 65 + j];
            featL[wave][lane] = sigm(s);
        }
        __syncthreads();
        float q = 0.f, k = 0.f;
#pragma unroll
        for (int i = 0; i < 28; i++) {
            float fv = featL[wave][i];
            q += fv * wqL[lane * 29 + i];
            k += fv * wkL[lane * 29 + i];
        }
        Qb[row * 64 + lane] = (ushort_t)f2bf(q * 0.125f);  // fold 1/sqrt(64)
        Kb[row * 64 + lane] = (ushort_t)f2bf(k);
        if (lane == 0) {
            float c = bcv;
#pragma unroll
            for (int i = 0; i < 28; i++) c += featL[wave][i] * wcL[i];
            charge0[row] = sigm(c);
        }
        __syncthreads();
    }
}

DEV void tri_decode(int r, int& ti, int& tj) {
    int t = (int)((sqrtf(8.f * (float)r + 1.f) - 1.f) * 0.5f);
    while ((t + 1) * (t + 2) / 2 <= r) t++;
    while (t * (t + 1) / 2 > r) t--;
    ti = t;
    tj = r - t * (t + 1) / 2;
}

// ---------------- K2: compat = (Q/8)·K, causal 128x128 tiles, bf16
__global__ __launch_bounds__(256) void k_compat(const ushort_t* __restrict__ Qb,
                                                const ushort_t* __restrict__ Kb,
                                                ushort_t* __restrict__ compat) {
    int bid = blockIdx.x;
    int b = bid / 136, r = bid % 136, ti, tj;
    tri_decode(r, ti, tj);
    int wave = threadIdx.x >> 6, lane = threadIdx.x & 63;
    int l16 = lane & 15, quad = lane >> 4;
    int rbase = b * 2048 + ti * 128 + wave * 32;
    int cbase = b * 2048 + tj * 128;
    f32x4 acc[2][8] = {};
#pragma unroll
    for (int kc = 0; kc < 64; kc += 32) {
        int ko = kc + quad * 8;
        bf16x8 af[2], bf[8];
#pragma unroll
        for (int f = 0; f < 2; f++)
            af[f] = *reinterpret_cast<const bf16x8*>(Qb + (long)(rbase + f * 16 + l16) * 64 + ko);
#pragma unroll
        for (int f = 0; f < 8; f++)
            bf[f] = *reinterpret_cast<const bf16x8*>(Kb + (long)(cbase + f * 16 + l16) * 64 + ko);
#pragma unroll
        for (int i = 0; i < 2; i++)
#pragma unroll
            for (int j = 0; j < 8; j++)
                acc[i][j] = __builtin_amdgcn_mfma_f32_16x16x32_bf16(af[i], bf[j], acc[i][j], 0, 0, 0);
    }
    int colt = tj * 128;
#pragma unroll
    for (int i = 0; i < 2; i++)
#pragma unroll
        for (int j = 0; j < 8; j++)
#pragma unroll
            for (int rr = 0; rr < 4; rr++) {
                long rowg = rbase + i * 16 + quad * 4 + rr;
                int col = colt + j * 16 + l16;
                compat[rowg * 2048 + col] = (ushort_t)f2bf(acc[i][j][rr]);
            }
}

// ---------------- K3: single-pass strip kernel, iteration T.
// 1024 blocks = 4 batches x 256 pairs {A rows [4p,4p+4), B rows [2044-4p,2048-4p)}.
// Block-uniform guards skip fully-masked spans (A chunk0 beyond r0A, B chunk1
// beyond r0B) - loads and exps skipped, zero-init arrays keep partials exact.
template <int T>
__global__ __launch_bounds__(256, 2) void k_strip(const ushort_t* __restrict__ compat,
        const float4* __restrict__ charges4, const float* __restrict__ stepp,
        float* __restrict__ Rpart) {
    __shared__ float chR[4][8];   // [comp][row: 0-3 A, 4-7 B]
    __shared__ float red[4][8], Li[8];
    int bid = blockIdx.x, tid = threadIdx.x;
    int b = bid >> 8, pi = bid & 255;
    int r0A = pi * 4, r0B = 2044 - pi * 4;
    float step = stepp[0];
    if (T > 0 && tid < 8) {
        int row = (tid < 4) ? (r0A + tid) : (r0B + tid - 4);
        float4 c4 = charges4[b * 2048 + row];
        chR[0][tid] = step * c4.x;
        if (T > 1) chR[1][tid] = step * c4.y;
        if (T > 2) chR[2][tid] = step * c4.z;
        if (T > 3) chR[3][tid] = step * c4.w;
    }
    __syncthreads();
    int w = tid >> 6, lane = tid & 63;
    int c0 = tid * 4;
    const ushort_t* base = compat + (long)(b * 2048) * 2048;

    float pA[4][4] = {}, pB0[4][4] = {}, pB1[4][4] = {};
    float SA[4] = {}, SB[4] = {};

    // ---- chunk 0: cols [c0, c0+4) in [0,1024)
    {
        float cx[4] = {}, cy[4] = {}, cz[4] = {}, cw[4] = {};
        if (T > 0) {
#pragma unroll
            for (int k = 0; k < 4; k++) {
                float4 c = charges4[b * 2048 + c0 + k];
                cx[k] = c.x;
                if (T > 1) cy[k] = c.y;
                if (T > 2) cz[k] = c.z;
                if (T > 3) cw[k] = c.w;
            }
        }
        if (c0 <= r0A + 3) {   // block-uniform-ish guard: skip fully-masked A spans
#pragma unroll
            for (int rr = 0; rr < 4; rr++) {
                u16x4 v = *reinterpret_cast<const u16x4*>(base + (long)(r0A + rr) * 2048 + c0);
#pragma unroll
                for (int k = 0; k < 4; k++) {
                    float sg = 1.f;
                    if (T > 0) sg += chR[0][rr] * cx[k];
                    if (T > 1) sg += chR[1][rr] * cy[k];
                    if (T > 2) sg += chR[2][rr] * cz[k];
                    if (T > 3) sg += chR[3][rr] * cw[k];
                    float p = (c0 + k <= r0A + rr) ? __expf(bf2f(v[k]) * sg) : 0.f;
                    pA[rr][k] = p;
                    SA[rr] += p;
                }
            }
        }
#pragma unroll
        for (int rr = 0; rr < 4; rr++) {
            u16x4 v = *reinterpret_cast<const u16x4*>(base + (long)(r0B + rr) * 2048 + c0);
#pragma unroll
            for (int k = 0; k < 4; k++) {
                float sg = 1.f;
                if (T > 0) sg += chR[0][4 + rr] * cx[k];
                if (T > 1) sg += chR[1][4 + rr] * cy[k];
                if (T > 2) sg += chR[2][4 + rr] * cz[k];
                if (T > 3) sg += chR[3][4 + rr] * cw[k];
                float p = __expf(bf2f(v[k]) * sg);   // col<1024 <= r0B always
                pB0[rr][k] = p;
                SB[rr] += p;
            }
        }
    }
    // ---- chunk 1: cols 1024+[c0, c0+4), B rows only (masked, guarded)
    if (1024 + c0 <= r0B + 3) {
        float cx[4] = {}, cy[4] = {}, cz[4] = {}, cw[4] = {};
        if (T > 0) {
#pragma unroll
            for (int k = 0; k < 4; k++) {
                float4 c = charges4[b * 2048 + 1024 + c0 + k];
                cx[k] = c.x;
                if (T > 1) cy[k] = c.y;
                if (T > 2) cz[k] = c.z;
                if (T > 3) cw[k] = c.w;
            }
        }
#pragma unroll
        for (int rr = 0; rr < 4; rr++) {
            u16x4 v = *reinterpret_cast<const u16x4*>(base + (long)(r0B + rr) * 2048 + 1024 + c0);
#pragma unroll
            for (int k = 0; k < 4; k++) {
                float sg = 1.f;
                if (T > 0) sg += chR[0][4 + rr] * cx[k];
                if (T > 1) sg += chR[1][4 + rr] * cy[k];
                if (T > 2) sg += chR[2][4 + rr] * cz[k];
                if (T > 3) sg += chR[3][4 + rr] * cw[k];
                float p = (1024 + c0 + k <= r0B + rr) ? __expf(bf2f(v[k]) * sg) : 0.f;
                pB1[rr][k] = p;
                SB[rr] += p;
            }
        }
    }
    // ---- reduce row sums -> Li[8]
#pragma unroll
    for (int rr = 0; rr < 4; rr++) {
        float s = SA[rr];
        s += __shfl_xor(s, 1); s += __shfl_xor(s, 2); s += __shfl_xor(s, 4);
        s += __shfl_xor(s, 8); s += __shfl_xor(s, 16); s += __shfl_xor(s, 32);
        if (lane == 0) red[w][rr] = s;
        float t = SB[rr];
        t += __shfl_xor(t, 1); t += __shfl_xor(t, 2); t += __shfl_xor(t, 4);
        t += __shfl_xor(t, 8); t += __shfl_xor(t, 16); t += __shfl_xor(t, 32);
        if (lane == 0) red[w][4 + rr] = t;
    }
    __syncthreads();
    if (tid < 8) Li[tid] = 1.f / fmaxf(red[0][tid] + red[1][tid] + red[2][tid] + red[3][tid], 1e-30f);
    __syncthreads();
    float liA0 = Li[0], liA1 = Li[1], liA2 = Li[2], liA3 = Li[3];
    float liB0 = Li[4], liB1 = Li[5], liB2 = Li[6], liB3 = Li[7];
    float4 o0, o1;
    float* po0 = (float*)&o0;
    float* po1 = (float*)&o1;
#pragma unroll
    for (int k = 0; k < 4; k++) {
        po0[k] = pA[0][k] * liA0 + pA[1][k] * liA1 + pA[2][k] * liA2 + pA[3][k] * liA3
               + pB0[0][k] * liB0 + pB0[1][k] * liB1 + pB0[2][k] * liB2 + pB0[3][k] * liB3;
        po1[k] = pB1[0][k] * liB0 + pB1[1][k] * liB1 + pB1[2][k] * liB2 + pB1[3][k] * liB3;
    }
    *reinterpret_cast<float4*>(&Rpart[(long)bid * 2048 + c0]) = o0;
    *reinterpret_cast<float4*>(&Rpart[(long)bid * 2048 + 1024 + c0]) = o1;
}

// ---------------- K4: charge update T. 256 blocks; block = 32 cols x 8 partial-groups.
template <int T>
__global__ __launch_bounds__(256) void k_charge(const float* __restrict__ Rpart,
        const float* __restrict__ charge0, float4* __restrict__ charges4,
        const float* __restrict__ decayp) {
    __shared__ float s8[8][33];
    int g = threadIdx.x >> 5, cl = threadIdx.x & 31;
    int m = blockIdx.x * 32 + cl;           // global col id in [0,8192)
    int b = m >> 11, col = m & 2047;
    const float* rp = Rpart + ((long)(b * 256 + g * 32) * 2048) + col;
    float s = 0.f;
#pragma unroll
    for (int i = 0; i < 32; i++) s += rp[(long)i * 2048];
    s8[g][cl] = s;
    __syncthreads();
    if (threadIdx.x < 32) {
        float t = 0.f;
#pragma unroll
        for (int gg = 0; gg < 8; gg++) t += s8[gg][threadIdx.x];
        int mm = blockIdx.x * 32 + threadIdx.x;
        float decay = decayp[0];
        float prev = (T == 1) ? charge0[mm] : ((const float*)&charges4[mm])[T - 2];
        ((float*)&charges4[mm])[T - 1] = prev * (1.f - decay * sigm(t - 1.f));
    }
}

// ---------------- K5: final pass, single-pass PV with deferred normalization.
// 1024 blocks = 4 batches x 256 pairs {A rows [4p,4p+4), B rows [2044-4p,2048-4p)}.
// 8 live rows/block; MFMA A rows 8-15 fed from a zero LDS row (pbuf[8]).
// unroll 4 on MFMA loops: <=4 VbT loads in flight (round-8 full unroll held 32
// -> 256 VGPR demand -> 58 MB scratch spill). acc scaled by 1/L at writeout.
// pbuf row stride 1032 shorts = 2064 B = 129*16: 16B-aligned, odd-16B -> 2-way alias max.
__global__ __launch_bounds__(256, 4) void k_stripPV(const ushort_t* __restrict__ compat,
        const float4* __restrict__ charges4, const float* __restrict__ stepp,
        const ushort_t* __restrict__ VbT, ushort_t* __restrict__ Abf) {
    __shared__ float chR[4][8], red[4][8], Li[8];
    __shared__ __align__(16) ushort_t pbuf[9][1032];
    int bid = blockIdx.x, tid = threadIdx.x;
    int b = bid >> 8, pi = bid & 255;
    int r0A = pi * 4, r0B = 2044 - pi * 4;
    float step = stepp[0];
    if (tid < 8) {
        int row = (tid < 4) ? (r0A + tid) : (r0B + tid - 4);
        float4 c4 = charges4[b * 2048 + row];
        chR[0][tid] = step * c4.x; chR[1][tid] = step * c4.y;
        chR[2][tid] = step * c4.z; chR[3][tid] = step * c4.w;
    }
    u16x4 zz = {0, 0, 0, 0};
    *reinterpret_cast<u16x4*>(&pbuf[8][tid * 4]) = zz;   // zero row for A-frag lanes 8-15
    __syncthreads();
    int w = tid >> 6, lane = tid & 63, l16 = lane & 15, quad = lane >> 4;
    int pr = (l16 < 8) ? l16 : 8;
    int c0 = tid * 4;
    const ushort_t* base = compat + (long)(b * 2048) * 2048;
    float S[8];
#pragma unroll
    for (int i = 0; i < 8; i++) S[i] = 0.f;
    f32x4 acc = {};

    // ---- chunk 0: cols [0,1024)
    {
        float cx[4], cy[4], cz[4], cw[4];
#pragma unroll
        for (int k = 0; k < 4; k++) {
            float4 c = charges4[b * 2048 + c0 + k];
            cx[k] = c.x; cy[k] = c.y; cz[k] = c.z; cw[k] = c.w;
        }
        if (c0 <= r0A + 3) {
#pragma unroll
            for (int i = 0; i < 4; i++) {
                u16x4 v = *reinterpret_cast<const u16x4*>(base + (long)(r0A + i) * 2048 + c0);
                u16x4 pv;
#pragma unroll
                for (int k = 0; k < 4; k++) {
                    float sg = 1.f + chR[0][i] * cx[k] + chR[1][i] * cy[k]
                                   + chR[2][i] * cz[k] + chR[3][i] * cw[k];
                    float p = (c0 + k <= r0A + i) ? __expf(bf2f(v[k]) * sg) : 0.f;
                    S[i] += p;
                    pv[k] = (ushort_t)f2bf(p);
                }
                *reinterpret_cast<u16x4*>(&pbuf[i][c0]) = pv;
            }
        } else {
#pragma unroll
            for (int i = 0; i < 4; i++) *reinterpret_cast<u16x4*>(&pbuf[i][c0]) = zz;
        }
#pragma unroll
        for (int i = 4; i < 8; i++) {
            u16x4 v = *reinterpret_cast<const u16x4*>(base + (long)(r0B + i - 4) * 2048 + c0);
            u16x4 pv;
#pragma unroll
            for (int k = 0; k < 4; k++) {
                float sg = 1.f + chR[0][i] * cx[k] + chR[1][i] * cy[k]
                               + chR[2][i] * cz[k] + chR[3][i] * cw[k];
                float p = __expf(bf2f(v[k]) * sg);   // col<1024 <= r0B always
                S[i] += p;
                pv[k] = (ushort_t)f2bf(p);
            }
            *reinterpret_cast<u16x4*>(&pbuf[i][c0]) = pv;
        }
    }
    __syncthreads();
#pragma unroll 4
    for (int k0 = 0; k0 < 1024; k0 += 32) {
        bf16x8 af = *reinterpret_cast<const bf16x8*>(&pbuf[pr][k0 + quad * 8]);
        bf16x8 vf = *reinterpret_cast<const bf16x8*>(
            VbT + (long)(w * 16 + l16) * 8192 + b * 2048 + k0 + quad * 8);
        acc = __builtin_amdgcn_mfma_f32_16x16x32_bf16(af, vf, acc, 0, 0, 0);
    }
    __syncthreads();
    // ---- chunk 1: cols [1024,2048): A rows zeroed; B rows masked (guarded)
    {
#pragma unroll
        for (int i = 0; i < 4; i++) *reinterpret_cast<u16x4*>(&pbuf[i][c0]) = zz;
        if (1024 + c0 <= r0B + 3) {
            float cx[4], cy[4], cz[4], cw[4];
#pragma unroll
            for (int k = 0; k < 4; k++) {
                float4 c = charges4[b * 2048 + 1024 + c0 + k];
                cx[k] = c.x; cy[k] = c.y; cz[k] = c.z; cw[k] = c.w;
            }
#pragma unroll
            for (int i = 4; i < 8; i++) {
                int grow = r0B + i - 4;
                u16x4 v = *reinterpret_cast<const u16x4*>(base + (long)grow * 2048 + 1024 + c0);
                u16x4 pv;
#pragma unroll
                for (int k = 0; k < 4; k++) {
                    float sg = 1.f + chR[0][i] * cx[k] + chR[1][i] * cy[k]
                                   + chR[2][i] * cz[k] + chR[3][i] * cw[k];
                    float p = (1024 + c0 + k <= grow) ? __expf(bf2f(v[k]) * sg) : 0.f;
                    S[i] += p;
                    pv[k] = (ushort_t)f2bf(p);
                }
                *reinterpret_cast<u16x4*>(&pbuf[i][c0]) = pv;
            }
        } else {
#pragma unroll
            for (int i = 4; i < 8; i++) *reinterpret_cast<u16x4*>(&pbuf[i][c0]) = zz;
        }
    }
    __syncthreads();
#pragma unroll 4
    for (int k0 = 0; k0 < 1024; k0 += 32) {
        bf16x8 af = *reinterpret_cast<const bf16x8*>(&pbuf[pr][k0 + quad * 8]);
        bf16x8 vf = *reinterpret_cast<const bf16x8*>(
            VbT + (long)(w * 16 + l16) * 8192 + b * 2048 + 1024 + k0 + quad * 8);
        acc = __builtin_amdgcn_mfma_f32_16x16x32_bf16(af, vf, acc, 0, 0, 0);
    }
    // ---- reduce S -> Li[8], scale acc, write rows 0-7
#pragma unroll
    for (int i = 0; i < 8; i++) {
        float s = S[i];
        s += __shfl_xor(s, 1); s += __shfl_xor(s, 2); s += __shfl_xor(s, 4);
        s += __shfl_xor(s, 8); s += __shfl_xor(s, 16); s += __shfl_xor(s, 32);
        if (lane == 0) red[w][i] = s;
    }
    __syncthreads();
    if (tid < 8) Li[tid] = 1.f / fmaxf(red[0][tid] + red[1][tid] + red[2][tid] + red[3][tid], 1e-30f);
    __syncthreads();
    if (quad < 2) {
#pragma unroll
        for (int rr = 0; rr < 4; rr++) {
            int row8 = quad * 4 + rr;   // 0..7
            int grow = (row8 < 4) ? (b * 2048 + r0A + row8) : (b * 2048 + r0B + row8 - 4);
            Abf[(long)grow * 64 + w * 16 + l16] = (ushort_t)f2bf(acc[rr] * Li[row8]);
        }
    }
}

// ---------------- K6: out = (Abf @ Wo^T) * 0.1, fp32 store
__global__ __launch_bounds__(256) void k_oproj(const ushort_t* __restrict__ Abf,
                                               const float* __restrict__ Wo,
                                               float* __restrict__ out) {
    int mt = blockIdx.x & 63, nt = blockIdx.x >> 6;
    int wave = threadIdx.x >> 6, lane = threadIdx.x & 63;
    int wm = wave >> 1, wn = wave & 1;
    int l16 = lane & 15, quad = lane >> 4;
    int row0 = mt * 128 + wm * 64;
    int col0 = nt * 128 + wn * 64;
    f32x4 acc[4][4] = {};
#pragma unroll
    for (int kc = 0; kc < 64; kc += 32) {
        int ko = kc + quad * 8;
        bf16x8 af[4], bfm[4];
#pragma unroll
        for (int f = 0; f < 4; f++)
            af[f] = *reinterpret_cast<const bf16x8*>(Abf + (long)(row0 + f * 16 + l16) * 64 + ko);
#pragma unroll
        for (int f = 0; f < 4; f++) bfm[f] = ld8f(Wo + (long)(col0 + f * 16 + l16) * 64 + ko);
#pragma unroll
        for (int i = 0; i < 4; i++)
#pragma unroll
            for (int j = 0; j < 4; j++)
                acc[i][j] = __builtin_amdgcn_mfma_f32_16x16x32_bf16(af[i], bfm[j], acc[i][j], 0, 0, 0);
    }
#pragma unroll
    for (int i = 0; i < 4; i++)
#pragma unroll
        for (int j = 0; j < 4; j++)
#pragma unroll
            for (int rr = 0; rr < 4; rr++) {
                long rowg = row0 + i * 16 + quad * 4 + rr;
                int colg = col0 + j * 16 + l16;
                out[rowg * 1024 + colg] = acc[i][j][rr] * 0.1f;
            }
}

extern "C" void kernel_launch(void* const* d_in, const int* in_sizes, int n_in,
                              void* d_out, int out_size, void* d_ws, size_t ws_size,
                              hipStream_t stream) {
    const float* hidden = (const float*)d_in[0];
    const float* W1 = (const float*)d_in[1];
    const float* b1 = (const float*)d_in[2];
    const float* W2 = (const float*)d_in[3];
    const float* b2 = (const float*)d_in[4];
    const float* Wq = (const float*)d_in[5];
    const float* Wk = (const float*)d_in[6];
    const float* Wc = (const float*)d_in[7];
    const float* bc = (const float*)d_in[8];
    const float* Wv = (const float*)d_in[9];
    const float* Wo = (const float*)d_in[10];
    const float* stepp = (const float*)d_in[11];
    const float* decayp = (const float*)d_in[12];

    char* ws = (char*)d_ws;
    size_t off = 0;
    auto alloc = [&](size_t bytes) {
        void* p = ws + off;
        off += (bytes + 255) & ~(size_t)255;
        return p;
    };
    ushort_t* compat = (ushort_t*)alloc(8192UL * 2048 * 2);   // 32 MiB bf16
    ushort_t* Wcat = (ushort_t*)alloc(128UL * 1024 * 2);      // W1;Wv bf16
    ushort_t* Qb = (ushort_t*)alloc(8192UL * 64 * 2);
    ushort_t* Kb = (ushort_t*)alloc(8192UL * 64 * 2);
    ushort_t* VbT = (ushort_t*)alloc(64UL * 8192 * 2);
    float* charge0 = (float*)alloc(8192UL * 4);
    float4* charges4 = (float4*)alloc(8192UL * 16);
    float* Rpart = (float*)alloc(1024UL * 2048 * 4);          // 8 MiB col partials
    ushort_t* Abf = (ushort_t*)alloc(8192UL * 64 * 2);        // 1 MiB normalized O
    (void)ws_size; (void)in_sizes; (void)n_in; (void)out_size;

    k_cvtW<<<64, 256, 0, stream>>>(W1, Wv, Wcat);
    k_fvfeat<<<512, 256, 0, stream>>>(hidden, Wcat, b1, W2, b2, Wq, Wk, Wc, bc,
                                      Qb, Kb, VbT, charge0);
    k_compat<<<544, 256, 0, stream>>>(Qb, Kb, compat);

    k_strip<0><<<1024, 256, 0, stream>>>(compat, charges4, stepp, Rpart);
    k_charge<1><<<256, 256, 0, stream>>>(Rpart, charge0, charges4, decayp);
    k_strip<1><<<1024, 256, 0, stream>>>(compat, charges4, stepp, Rpart);
    k_charge<2><<<256, 256, 0, stream>>>(Rpart, charge0, charges4, decayp);
    k_strip<2><<<1024, 256, 0, stream>>>(compat, charges4, stepp, Rpart);
    k_charge<3><<<256, 256, 0, stream>>>(Rpart, charge0, charges4, decayp);
    k_strip<3><<<1024, 256, 0, stream>>>(compat, charges4, stepp, Rpart);
    k_charge<4><<<256, 256, 0, stream>>>(Rpart, charge0, charges4, decayp);

    k_stripPV<<<1024, 256, 0, stream>>>(compat, charges4, stepp, VbT, Abf);
    k_oproj<<<512, 256, 0, stream>>>(Abf, Wo, (float*)d_out);
}